// Round 5
// baseline (1551.081 us; speedup 1.0000x reference)
//
#include <hip/hip_runtime.h>
#include <stdint.h>

#define Bz 4
#define Sz 1024
#define DIMz 4096
#define Hz 32
#define HDz 128
#define ALz 10

typedef unsigned short u16;
typedef __attribute__((ext_vector_type(8))) short short8;
typedef __attribute__((ext_vector_type(4))) float fx4;

__device__ __forceinline__ u16 f2b(float f){
  union { float f; unsigned u; } v; v.f = f;
  unsigned r = v.u + 0x7FFFu + ((v.u >> 16) & 1u);
  return (u16)(r >> 16);
}
__device__ __forceinline__ float b2f(u16 h){
  union { unsigned u; float f; } v; v.u = ((unsigned)h) << 16; return v.f;
}
__device__ __forceinline__ void gload16(const void* g, void* l){
  __builtin_amdgcn_global_load_lds(
    (const __attribute__((address_space(1))) uint32_t*)g,
    (__attribute__((address_space(3))) uint32_t*)l, 16, 0, 0);
}
__device__ __forceinline__ void bar(){
  asm volatile("" ::: "memory");
  __builtin_amdgcn_s_barrier();
  asm volatile("" ::: "memory");
}

// ---------- LDS swizzle helper (T2: byte ^= (row&7)<<4) ----------
__device__ __forceinline__ const short8* ldsRd(const u16* base, int rowBytes, int row, int colElem){
  unsigned byte = (unsigned)(row * rowBytes + colElem * 2);
  byte ^= (unsigned)((row & 7) << 4);
  return (const short8*)((const char*)base + byte);
}
__device__ __forceinline__ u16* psPtr(u16* base, int w, int row, int colElem){
  unsigned byte = (unsigned)(row * 128 + colElem * 2);
  byte ^= (unsigned)((row & 7) << 4);
  return (u16*)((char*)base + w * 2048 + byte);
}

// ---------- conversions ----------
__global__ void k_f2b_pad(const float* __restrict__ src, u16* __restrict__ dst,
                          int srcRows, int cols, int dstRows){
  size_t i = (size_t)blockIdx.x * 1024 + (size_t)threadIdx.x * 4;
  int row = (int)(i / cols);
  if (row < srcRows){
    fx4 v = *(const fx4*)(src + i);
    dst[i] = f2b(v[0]); dst[i+1] = f2b(v[1]); dst[i+2] = f2b(v[2]); dst[i+3] = f2b(v[3]);
  } else {
    dst[i] = 0; dst[i+1] = 0; dst[i+2] = 0; dst[i+3] = 0;
  }
}

__global__ void k_xcat(const float* __restrict__ x, const float* __restrict__ ad,
                       u16* __restrict__ dst){
  size_t i = (size_t)blockIdx.x * 1024 + (size_t)threadIdx.x * 4;
  int row = (int)(i >> 12);
  int col = (int)(i & 4095);
  const float* s = nullptr;
  if (row < 4096) s = x + i;
  else if (row < 4096 + Bz*ALz) s = ad + (size_t)(row - 4096) * DIMz + col;
  if (s){
    fx4 v = *(const fx4*)s;
    dst[i] = f2b(v[0]); dst[i+1] = f2b(v[1]); dst[i+2] = f2b(v[2]); dst[i+3] = f2b(v[3]);
  } else {
    dst[i] = 0; dst[i+1] = 0; dst[i+2] = 0; dst[i+3] = 0;
  }
}

__global__ void k_l1cat(const float* __restrict__ a, const float* __restrict__ b,
                        const float* __restrict__ c, u16* __restrict__ dst){
  size_t i = (size_t)blockIdx.x * 1024 + (size_t)threadIdx.x * 4;
  int row = (int)(i >> 12);
  int col = (int)(i & 4095);
  const float* s = nullptr;
  if (row < 16) s = a + (size_t)row * 4096 + col;
  else if (row < 32) s = b + (size_t)(row - 16) * 4096 + col;
  else if (row < 48) s = c + (size_t)(row - 32) * 4096 + col;
  if (s){
    fx4 v = *(const fx4*)s;
    dst[i] = f2b(v[0]); dst[i+1] = f2b(v[1]); dst[i+2] = f2b(v[2]); dst[i+3] = f2b(v[3]);
  } else {
    dst[i] = 0; dst[i+1] = 0; dst[i+2] = 0; dst[i+3] = 0;
  }
}

// ---------- 256x256 counted-vmcnt NT bf16 GEMM (T2+T3+T4+T5, 8 waves) ----------
// C[m][n] = sum_k A[m][k] * B[n][k].  M,N multiples of 256; K multiple of 64 (K>=128).
// LDS: 2 buffers x (A 256x64 + B 256x64) bf16 = 128 KB. 1 block/CU.
// Pipeline: prologue stages tiles 0,1; iteration tail stages t+2 into the buffer
// just consumed (barrier after phase-3 MFMAs guarantees all reads retired), then
// vmcnt(8): tile t+1 complete, t+2's 8 loads stay in flight. Never drains to 0.
__global__ __launch_bounds__(512, 2)
void gemm_nt256(const u16* __restrict__ A, const u16* __restrict__ Bm,
                void* __restrict__ Cp, int M, int N, int K, int outBf16, int nbx){
  __shared__ __align__(16) u16 lds[2][2][256][64];
  const int tid = threadIdx.x;
  const int l = tid & 63;
  const int w = tid >> 6;            // 0..7
  const int lrow = l & 15, lgrp = l >> 4;
  const int wm = w >> 2, wn = w & 3; // 2M x 4N wave grid

  // bijective XCD swizzle (nwg % 8 == 0 for all our grids)
  const int nwg = gridDim.x;
  const int cpx = nwg >> 3;
  const int swz = (blockIdx.x & 7) * cpx + (blockIdx.x >> 3);
  const int by = swz / nbx, bx = swz - by * nbx;
  const int bm = by << 8, bn = bx << 8;

  const u16* Abase = A + (size_t)bm * K;
  const u16* Bbase = Bm + (size_t)bn * K;
  const int nt = K >> 6;

  const fx4 fz = {0.f, 0.f, 0.f, 0.f};
  fx4 acc[8][4];
#pragma unroll
  for (int i = 0; i < 8; i++)
#pragma unroll
    for (int j = 0; j < 4; j++) acc[i][j] = fz;

  auto STAGE = [&](int buf, int t){
    const u16* Ab = Abase + t * 64;
    const u16* Bb = Bbase + t * 64;
    u16* dA = &lds[buf][0][0][0];
    u16* dB = &lds[buf][1][0][0];
#pragma unroll
    for (int r = 0; r < 4; r++){
      int c = r * 512 + tid;               // 0..2047
      int row = c >> 3, cs = c & 7;
      int off = (cs ^ (row & 7)) << 3;     // pre-swizzled source, linear LDS dest
      gload16(Ab + (size_t)row * K + off, dA + c * 8);
    }
#pragma unroll
    for (int r = 0; r < 4; r++){
      int c = r * 512 + tid;
      int row = c >> 3, cs = c & 7;
      int off = (cs ^ (row & 7)) << 3;
      gload16(Bb + (size_t)row * K + off, dB + c * 8);
    }
  };

  STAGE(0, 0);
  if (nt > 1){ STAGE(1, 1); asm volatile("s_waitcnt vmcnt(8)" ::: "memory"); }
  else       {              asm volatile("s_waitcnt vmcnt(0)" ::: "memory"); }
  bar();

  int cur = 0;
  for (int t = 0; t < nt; t++){
    const u16* As = &lds[cur][0][0][0];
    const u16* Bs = &lds[cur][1][0][0];
    short8 bf[4][2];
#pragma unroll
    for (int p = 0; p < 4; p++){
      if (p == 0){
#pragma unroll
        for (int nj = 0; nj < 4; nj++)
#pragma unroll
          for (int kk = 0; kk < 2; kk++)
            bf[nj][kk] = *ldsRd(Bs, 128, wn*64 + nj*16 + lrow, kk*32 + lgrp*8);
      }
      short8 af[2][2];
#pragma unroll
      for (int m2 = 0; m2 < 2; m2++)
#pragma unroll
        for (int kk = 0; kk < 2; kk++)
          af[m2][kk] = *ldsRd(As, 128, wm*128 + (p*2 + m2)*16 + lrow, kk*32 + lgrp*8);
      __builtin_amdgcn_s_setprio(1);
#pragma unroll
      for (int m2 = 0; m2 < 2; m2++)
#pragma unroll
        for (int nj = 0; nj < 4; nj++)
#pragma unroll
          for (int kk = 0; kk < 2; kk++)
            acc[p*2+m2][nj] = __builtin_amdgcn_mfma_f32_16x16x32_bf16(
                af[m2][kk], bf[nj][kk], acc[p*2+m2][nj], 0, 0, 0);
      __builtin_amdgcn_s_setprio(0);
      if (p < 3) bar();
    }
    bar();  // all waves' reads of buf[cur] retired (phase-3 MFMAs forced lgkm-complete)
    if (t + 2 < nt){
      STAGE(cur, t + 2);
      asm volatile("s_waitcnt vmcnt(8)" ::: "memory");  // tile t+1 landed; t+2 in flight
    } else if (t + 1 < nt){
      asm volatile("s_waitcnt vmcnt(0)" ::: "memory");
    }
    bar();
    cur ^= 1;
  }

  if (outBf16){
    u16* C = (u16*)Cp;
#pragma unroll
    for (int mi = 0; mi < 8; mi++)
#pragma unroll
      for (int r = 0; r < 4; r++){
        int gm = bm + wm*128 + mi*16 + lgrp*4 + r;
        u16* crow = C + (size_t)gm * N + bn + wn*64 + lrow;
#pragma unroll
        for (int nj = 0; nj < 4; nj++) crow[nj*16] = f2b(acc[mi][nj][r]);
      }
  } else {
    float* C = (float*)Cp;
#pragma unroll
    for (int mi = 0; mi < 8; mi++)
#pragma unroll
      for (int r = 0; r < 4; r++){
        int gm = bm + wm*128 + mi*16 + lgrp*4 + r;
        float* crow = C + (size_t)gm * N + bn + wn*64 + lrow;
#pragma unroll
        for (int nj = 0; nj < 4; nj++) crow[nj*16] = acc[mi][nj][r];
      }
  }
}

// ---------- 128x128 NT bf16 GEMM (kept for small-N LoRA gemms) ----------
__global__ __launch_bounds__(256)
void gemm_nt(const u16* __restrict__ A, const u16* __restrict__ Bm, void* __restrict__ Cp,
             int M, int N, int K, int outBf16){
  __shared__ __align__(16) u16 As[128][64];
  __shared__ __align__(16) u16 Bs[128][64];
  const int tid = threadIdx.x;
  const int w = tid >> 6, l = tid & 63;
  const int lrow = l & 15, lgrp = l >> 4;
  const int bm = blockIdx.y * 128, bn = blockIdx.x * 128;
  const int wr = (w >> 1) * 64, wc = (w & 1) * 64;

  const fx4 fz = {0.f, 0.f, 0.f, 0.f};
  fx4 acc[4][4];
#pragma unroll
  for (int i = 0; i < 4; i++)
#pragma unroll
    for (int j = 0; j < 4; j++) acc[i][j] = fz;

  const u16* Abase = A + (size_t)bm * K;
  const u16* Bbase = Bm + (size_t)bn * K;

  for (int k0 = 0; k0 < K; k0 += 64){
    __syncthreads();
#pragma unroll
    for (int i = 0; i < 4; i++){
      int c = i * 256 + tid;
      int row = c >> 3, cs = c & 7;
      int off = (cs ^ (row & 7)) << 3;
      gload16(Abase + (size_t)row * K + k0 + off, ((u16*)As) + c * 8);
      gload16(Bbase + (size_t)row * K + k0 + off, ((u16*)Bs) + c * 8);
    }
    __syncthreads();
#pragma unroll
    for (int kk = 0; kk < 2; kk++){
      short8 a[4], b[4];
#pragma unroll
      for (int i = 0; i < 4; i++) a[i] = *ldsRd(&As[0][0], 128, wr + i*16 + lrow, kk*32 + lgrp*8);
#pragma unroll
      for (int j = 0; j < 4; j++) b[j] = *ldsRd(&Bs[0][0], 128, wc + j*16 + lrow, kk*32 + lgrp*8);
#pragma unroll
      for (int i = 0; i < 4; i++)
#pragma unroll
        for (int j = 0; j < 4; j++)
          acc[i][j] = __builtin_amdgcn_mfma_f32_16x16x32_bf16(a[i], b[j], acc[i][j], 0, 0, 0);
    }
  }

  if (outBf16){
    u16* C = (u16*)Cp;
#pragma unroll
    for (int i = 0; i < 4; i++)
#pragma unroll
      for (int r = 0; r < 4; r++){
        int gm = bm + wr + i*16 + lgrp*4 + r;
        u16* crow = C + (size_t)gm * N + bn + wc + lrow;
#pragma unroll
        for (int j = 0; j < 4; j++) crow[j*16] = f2b(acc[i][j][r]);
      }
  } else {
    float* C = (float*)Cp;
#pragma unroll
    for (int i = 0; i < 4; i++)
#pragma unroll
      for (int r = 0; r < 4; r++){
        int gm = bm + wr + i*16 + lgrp*4 + r;
        float* crow = C + (size_t)gm * N + bn + wc + lrow;
#pragma unroll
        for (int j = 0; j < 4; j++) crow[j*16] = acc[i][j][r];
      }
  }
}

// ---------- LoRA rank-16 add ----------
__global__ void k_lora_add_b(u16* __restrict__ y, const float* __restrict__ t,
                             const float* __restrict__ l2, int roff){
  int o = blockIdx.x * 256 + threadIdx.x;
  int m = blockIdx.y;
  const fx4* tv = (const fx4*)(t + (size_t)m * 128 + roff);
  const fx4* lv = (const fx4*)(l2 + (size_t)o * 16);
  float s = 0.f;
#pragma unroll
  for (int r = 0; r < 4; r++){
    fx4 a = tv[r], b = lv[r];
    s += a[0]*b[0] + a[1]*b[1] + a[2]*b[2] + a[3]*b[3];
  }
  size_t idx = (size_t)m * DIMz + o;
  y[idx] = f2b(b2f(y[idx]) + s);
}

__global__ void k_lora_add_f(float* __restrict__ y, const float* __restrict__ t,
                             const float* __restrict__ l2, int roff){
  int o = blockIdx.x * 256 + threadIdx.x;
  int m = blockIdx.y;
  const fx4* tv = (const fx4*)(t + (size_t)m * 128 + roff);
  const fx4* lv = (const fx4*)(l2 + (size_t)o * 16);
  float s = 0.f;
#pragma unroll
  for (int r = 0; r < 4; r++){
    fx4 a = tv[r], b = lv[r];
    s += a[0]*b[0] + a[1]*b[1] + a[2]*b[2] + a[3]*b[3];
  }
  y[(size_t)m * DIMz + o] += s;
}

// ---------- RoPE + (B,S,DIM)->(B,H,S,HD) ----------
__global__ void k_rope(const u16* __restrict__ x, u16* __restrict__ out,
                       const float* __restrict__ fcos, const float* __restrict__ fsin){
  int m = blockIdx.x;
  int b = m >> 10, s = m & 1023;
#pragma unroll
  for (int i = 0; i < 8; i++){
    int p = i * 256 + threadIdx.x;
    int h = p >> 6, j = p & 63;
    size_t xi = (size_t)m * DIMz + h * HDz + 2 * j;
    float r = b2f(x[xi]), im = b2f(x[xi + 1]);
    float c = fcos[s * 64 + j], sn = fsin[s * 64 + j];
    size_t oi = (((size_t)b * Hz + h) * Sz + s) * HDz + 2 * j;
    out[oi]     = f2b(r * c - im * sn);
    out[oi + 1] = f2b(r * sn + im * c);
  }
}

// ---------- V: (B,S,H,HD) -> Vt (B,H,HD,S) ----------
__global__ void k_vtrans(const u16* __restrict__ x, u16* __restrict__ vt){
  __shared__ __align__(16) u16 tile[64][128];
  int bh = blockIdx.y;
  int b = bh >> 5, h = bh & 31;
  int s0 = blockIdx.x * 64;
  int tid = threadIdx.x;
#pragma unroll
  for (int i = 0; i < 4; i++){
    int c = i * 256 + tid;
    int ss = c >> 4, d8 = (c & 15) << 3;
    *(short8*)&tile[ss][d8] =
      *(const short8*)&x[(size_t)(b * Sz + s0 + ss) * DIMz + h * HDz + d8];
  }
  __syncthreads();
#pragma unroll
  for (int i = 0; i < 4; i++){
    int c = i * 256 + tid;
    int d = c >> 3, s8 = (c & 7) << 3;
    short8 v;
#pragma unroll
    for (int k = 0; k < 8; k++) v[k] = (short)tile[s8 + k][d];
    *(short8*)&vt[((size_t)bh * HDz + d) * Sz + s0 + s8] = v;
  }
}

// ---------- adapter K/V reshape ----------
__global__ void k_adresh(const u16* __restrict__ akf, const u16* __restrict__ avf,
                         u16* __restrict__ AK, u16* __restrict__ AVt){
  int bh = blockIdx.x;
  int b = bh >> 5, h = bh & 31;
  int tid = threadIdx.x;
#pragma unroll
  for (int i = 0; i < 8; i++){
    int e = i * 256 + tid;
    int jj = e >> 7, d = e & 127;
    u16 v = (jj < ALz) ? akf[(size_t)(b * ALz + jj) * DIMz + h * HDz + d] : (u16)0;
    AK[((size_t)bh * 16 + jj) * HDz + d] = v;
  }
#pragma unroll
  for (int i = 0; i < 16; i++){
    int e = i * 256 + tid;
    int d = e >> 5, jj = e & 31;
    u16 v = (jj < ALz) ? avf[(size_t)(b * ALz + jj) * DIMz + h * HDz + d] : (u16)0;
    AVt[((size_t)bh * HDz + d) * 32 + jj] = v;
  }
}

// ---------- flash attention + gated adapter attention ----------
__global__ __launch_bounds__(256)
void k_attn(const u16* __restrict__ Q, const u16* __restrict__ Kg,
            const u16* __restrict__ Vt, const u16* __restrict__ AKg,
            const u16* __restrict__ AVg, const float* __restrict__ gate,
            u16* __restrict__ outp){
  __shared__ __align__(16) u16 Ks[64][128];
  __shared__ __align__(16) u16 Vs[128][64];
  __shared__ __align__(16) u16 Ps[4][16][64];

  const int bh = blockIdx.y;
  const int b = bh >> 5, h = bh & 31;
  const int q0 = blockIdx.x * 64;
  const int tid = threadIdx.x;
  const int w = tid >> 6, l = tid & 63;
  const int lrow = l & 15, lgrp = l >> 4;

  const u16* Qb = Q  + (size_t)bh * (Sz * HDz) + (size_t)q0 * HDz;
  const u16* Kb = Kg + (size_t)bh * (Sz * HDz);
  const u16* Vb = Vt + (size_t)bh * (HDz * Sz);
  u16* PsB = &Ps[0][0][0];

  short8 aq[4];
#pragma unroll
  for (int kk = 0; kk < 4; kk++)
    aq[kk] = *(const short8*)&Qb[(size_t)(w*16 + lrow) * HDz + kk*32 + lgrp*8];

  const fx4 fz = {0.f, 0.f, 0.f, 0.f};
  fx4 o[8];
#pragma unroll
  for (int i = 0; i < 8; i++) o[i] = fz;
  float mrow[4], lsum[4];
#pragma unroll
  for (int r = 0; r < 4; r++){ mrow[r] = -1e30f; lsum[r] = 0.f; }

  const float scale = 0.088388347648318447f; // 1/sqrt(128)
  const int qrowbase = q0 + w * 16 + lgrp * 4;
  const int ktiles = blockIdx.x + 1;

  for (int kt = 0; kt < ktiles; kt++){
    const int k0 = kt * 64;
    __syncthreads();
#pragma unroll
    for (int i = 0; i < 4; i++){
      int c = i * 256 + tid;
      int row = c >> 4, cs = c & 15;
      int gcs = cs ^ (row & 7);
      gload16(Kb + (size_t)(k0 + row) * HDz + gcs * 8, ((u16*)Ks) + c * 8);
    }
#pragma unroll
    for (int i = 0; i < 4; i++){
      int c = i * 256 + tid;
      int row = c >> 3, cs = c & 7;
      int gcs = cs ^ (row & 7);
      gload16(Vb + (size_t)row * Sz + k0 + gcs * 8, ((u16*)Vs) + c * 8);
    }
    __syncthreads();

    fx4 sc[4];
#pragma unroll
    for (int j = 0; j < 4; j++) sc[j] = fz;
#pragma unroll
    for (int kk = 0; kk < 4; kk++){
#pragma unroll
      for (int j = 0; j < 4; j++){
        short8 bk = *ldsRd(&Ks[0][0], 256, j*16 + lrow, kk*32 + lgrp*8);
        sc[j] = __builtin_amdgcn_mfma_f32_16x16x32_bf16(aq[kk], bk, sc[j], 0, 0, 0);
      }
    }
    const int last = (kt == ktiles - 1);
    float tm[4];
#pragma unroll
    for (int r = 0; r < 4; r++){
      float mx = -1e30f;
#pragma unroll
      for (int j = 0; j < 4; j++){
        float v = sc[j][r] * scale;
        if (last){
          int kcol = k0 + j*16 + lrow;
          if (kcol > qrowbase + r) v = -1e30f;
        }
        sc[j][r] = v;
        mx = fmaxf(mx, v);
      }
#pragma unroll
      for (int d = 1; d < 16; d <<= 1) mx = fmaxf(mx, __shfl_xor(mx, d));
      tm[r] = mx;
    }
    float esc[4];
#pragma unroll
    for (int r = 0; r < 4; r++){
      float nm = fmaxf(mrow[r], tm[r]);
      esc[r] = __expf(mrow[r] - nm);
      mrow[r] = nm;
      float s = 0.f;
#pragma unroll
      for (int j = 0; j < 4; j++){
        float p = __expf(sc[j][r] - nm);
        sc[j][r] = p;
        s += p;
      }
#pragma unroll
      for (int d = 1; d < 16; d <<= 1) s += __shfl_xor(s, d);
      lsum[r] = lsum[r] * esc[r] + s;
    }
#pragma unroll
    for (int j = 0; j < 8; j++)
#pragma unroll
      for (int r = 0; r < 4; r++) o[j][r] *= esc[r];
#pragma unroll
    for (int j = 0; j < 4; j++)
#pragma unroll
      for (int r = 0; r < 4; r++)
        *psPtr(PsB, w, lgrp*4 + r, j*16 + lrow) = f2b(sc[j][r]);
#pragma unroll
    for (int kk = 0; kk < 2; kk++){
      short8 ap = *(const short8*)psPtr(PsB, w, lrow, kk*32 + lgrp*8);
#pragma unroll
      for (int j = 0; j < 8; j++){
        short8 bv = *ldsRd(&Vs[0][0], 128, j*16 + lrow, kk*32 + lgrp*8);
        o[j] = __builtin_amdgcn_mfma_f32_16x16x32_bf16(ap, bv, o[j], 0, 0, 0);
      }
    }
  }

#pragma unroll
  for (int j = 0; j < 8; j++)
#pragma unroll
    for (int r = 0; r < 4; r++) o[j][r] /= lsum[r];

  fx4 s2 = fz;
  const u16* AKb = AKg + (size_t)bh * (16 * HDz);
#pragma unroll
  for (int kk = 0; kk < 4; kk++){
    short8 bk = *(const short8*)&AKb[(size_t)lrow * HDz + kk*32 + lgrp*8];
    s2 = __builtin_amdgcn_mfma_f32_16x16x32_bf16(aq[kk], bk, s2, 0, 0, 0);
  }
  const float g = tanhf(gate[h]);
#pragma unroll
  for (int r = 0; r < 4; r++){
    float v = s2[r] * scale;
    if (lrow >= ALz) v = -1e30f;
    float mx = v;
#pragma unroll
    for (int d = 1; d < 16; d <<= 1) mx = fmaxf(mx, __shfl_xor(mx, d));
    float p = __expf(v - mx);
    float s = p;
#pragma unroll
    for (int d = 1; d < 16; d <<= 1) s += __shfl_xor(s, d);
    float p2 = g * p / s;
    *psPtr(PsB, w, lgrp*4 + r, lrow) = f2b(p2);
    *psPtr(PsB, w, lgrp*4 + r, 16 + lrow) = 0;
  }
  {
    const u16* AVb = AVg + (size_t)bh * (HDz * 32);
    short8 ap = *(const short8*)psPtr(PsB, w, lrow, lgrp*8);
#pragma unroll
    for (int j = 0; j < 8; j++){
      short8 bv = *(const short8*)&AVb[(size_t)(j*16 + lrow) * 32 + lgrp*8];
      o[j] = __builtin_amdgcn_mfma_f32_16x16x32_bf16(ap, bv, o[j], 0, 0, 0);
    }
  }

  u16* ob = outp + (size_t)(b * Sz + q0) * DIMz + h * HDz;
#pragma unroll
  for (int j = 0; j < 8; j++)
#pragma unroll
    for (int r = 0; r < 4; r++){
      int row = w*16 + lgrp*4 + r;
      ob[(size_t)row * DIMz + j*16 + lrow] = f2b(o[j][r]);
    }
}

// ---------- host ----------
extern "C" void kernel_launch(void* const* d_in, const int* in_sizes, int n_in,
                              void* d_out, int out_size, void* d_ws, size_t ws_size,
                              hipStream_t stream){
  const float* x    = (const float*)d_in[0];
  const float* adap = (const float*)d_in[1];
  const float* wq   = (const float*)d_in[2];
  const float* wk   = (const float*)d_in[3];
  const float* wv   = (const float*)d_in[4];
  const float* wo   = (const float*)d_in[5];
  const float* lq1  = (const float*)d_in[6];
  const float* lq2  = (const float*)d_in[7];
  const float* lk1  = (const float*)d_in[8];
  const float* lk2  = (const float*)d_in[9];
  const float* lv1  = (const float*)d_in[10];
  const float* lv2  = (const float*)d_in[11];
  const float* lo1  = (const float*)d_in[12];
  const float* lo2  = (const float*)d_in[13];
  const float* gate = (const float*)d_in[14];
  const float* fcos = (const float*)d_in[15];
  const float* fsin = (const float*)d_in[16];

  const size_t MB = 1024 * 1024;
  char* ws = (char*)d_ws;
  u16*  Xcat = (u16*)(ws);                 // 4352x4096 bf16 (34 MB); later Q
  u16*  Wb   = (u16*)(ws + 34 * MB);       // 32 MB; later K
  u16*  xq   = (u16*)(ws + 66 * MB);       // 34 MB; later attn_out
  u16*  xk   = (u16*)(ws + 100 * MB);      // 34 MB
  u16*  xv   = (u16*)(ws + 134 * MB);      // 34 MB
  u16*  Vt   = (u16*)(ws + 168 * MB);      // 32 MB; t (f32, 2.1 MB) aliases here (disjoint lifetimes)
  float* t   = (float*)(ws + 168 * MB);
  u16*  l1b  = (u16*)(ws + 200 * MB);      // 1 MB
  u16*  AKb  = (u16*)(ws + 201 * MB);      // 0.5 MB
  u16*  AVb  = (u16*)(ws + 201 * MB + 512 * 1024); // 1 MB
  u16*  Qb = Xcat;
  u16*  Kb = Wb;
  u16*  attn = xq;
  float* out = (float*)d_out;

  dim3 blk(256);
  const int MCAT = 4352;  // 4096 + 40 adapter rows, padded to x256

  k_xcat<<<dim3(MCAT * 4096 / 1024), blk, 0, stream>>>(x, adap, Xcat);

  // Q/K/V projections: 256^2 counted-vmcnt GEMM (grid 16x17=272, %8==0)
  k_f2b_pad<<<dim3(4096 * 4096 / 1024), blk, 0, stream>>>(wq, Wb, 4096, 4096, 4096);
  gemm_nt256<<<dim3(272), dim3(512), 0, stream>>>(Xcat, Wb, xq, MCAT, 4096, 4096, 1, 16);
  k_f2b_pad<<<dim3(4096 * 4096 / 1024), blk, 0, stream>>>(wk, Wb, 4096, 4096, 4096);
  gemm_nt256<<<dim3(272), dim3(512), 0, stream>>>(Xcat, Wb, xk, MCAT, 4096, 4096, 1, 16);
  k_f2b_pad<<<dim3(4096 * 4096 / 1024), blk, 0, stream>>>(wv, Wb, 4096, 4096, 4096);
  gemm_nt256<<<dim3(272), dim3(512), 0, stream>>>(Xcat, Wb, xv, MCAT, 4096, 4096, 1, 16);

  // LoRA l1 (q,k,v concatenated, N=128): small 128^2 kernel; t lives before Vt
  k_l1cat<<<dim3(128 * 4096 / 1024), blk, 0, stream>>>(lq1, lk1, lv1, l1b);
  gemm_nt<<<dim3(1, 33), blk, 0, stream>>>(Xcat, l1b, t, 4224, 128, 4096, 0);
  k_lora_add_b<<<dim3(16, 4096), blk, 0, stream>>>(xq, t, lq2, 0);
  k_lora_add_b<<<dim3(16, 4096), blk, 0, stream>>>(xk, t, lk2, 16);
  k_lora_add_b<<<dim3(16, 4096), blk, 0, stream>>>(xv, t, lv2, 32);

  k_rope<<<dim3(4096), blk, 0, stream>>>(xq, Qb, fcos, fsin);
  k_rope<<<dim3(4096), blk, 0, stream>>>(xk, Kb, fcos, fsin);
  k_vtrans<<<dim3(16, 128), blk, 0, stream>>>(xv, Vt);
  k_adresh<<<dim3(128), blk, 0, stream>>>(xk + (size_t)4096 * 4096,
                                          xv + (size_t)4096 * 4096, AKb, AVb);

  k_attn<<<dim3(16, 128), blk, 0, stream>>>(Qb, Kb, Vt, AKb, AVb, gate, attn);

  // output projection (M=4096, grid 16x16=256) + LoRA (t reuses Vt space; Vt dead)
  k_f2b_pad<<<dim3(4096 * 4096 / 1024), blk, 0, stream>>>(wo, Wb, 4096, 4096, 4096);
  gemm_nt256<<<dim3(256), dim3(512), 0, stream>>>(attn, Wb, out, 4096, 4096, 4096, 0, 16);
  k_f2b_pad<<<dim3(128 * 4096 / 1024), blk, 0, stream>>>(lo1, l1b, 16, 4096, 128);
  gemm_nt<<<dim3(1, 32), blk, 0, stream>>>(attn, l1b, t, 4096, 128, 4096, 0);
  k_lora_add_f<<<dim3(16, 4096), blk, 0, stream>>>(out, t, lo2, 0);
}

// Round 6
// 1455.340 us; speedup vs baseline: 1.0658x; 1.0658x over previous
//
#include <hip/hip_runtime.h>
#include <stdint.h>

#define Bz 4
#define Sz 1024
#define DIMz 4096
#define Hz 32
#define HDz 128
#define ALz 10

typedef unsigned short u16;
typedef __attribute__((ext_vector_type(8))) short short8;
typedef __attribute__((ext_vector_type(4))) float fx4;

__device__ __forceinline__ u16 f2b(float f){
  union { float f; unsigned u; } v; v.f = f;
  unsigned r = v.u + 0x7FFFu + ((v.u >> 16) & 1u);
  return (u16)(r >> 16);
}
__device__ __forceinline__ float b2f(u16 h){
  union { unsigned u; float f; } v; v.u = ((unsigned)h) << 16; return v.f;
}
__device__ __forceinline__ void gload16(const void* g, void* l){
  __builtin_amdgcn_global_load_lds(
    (const __attribute__((address_space(1))) uint32_t*)g,
    (__attribute__((address_space(3))) uint32_t*)l, 16, 0, 0);
}
__device__ __forceinline__ void bar(){
  asm volatile("" ::: "memory");
  __builtin_amdgcn_s_barrier();
  asm volatile("" ::: "memory");
}

// ---------- LDS swizzle helper (T2: byte ^= (row&7)<<4) ----------
__device__ __forceinline__ const short8* ldsRd(const u16* base, int rowBytes, int row, int colElem){
  unsigned byte = (unsigned)(row * rowBytes + colElem * 2);
  byte ^= (unsigned)((row & 7) << 4);
  return (const short8*)((const char*)base + byte);
}
__device__ __forceinline__ u16* psPtr(u16* base, int w, int row, int colElem){
  unsigned byte = (unsigned)(row * 128 + colElem * 2);
  byte ^= (unsigned)((row & 7) << 4);
  return (u16*)((char*)base + w * 2048 + byte);
}

// ---------- conversions ----------
__global__ void k_f2b_pad(const float* __restrict__ src, u16* __restrict__ dst,
                          int srcRows, int cols, int dstRows){
  size_t i = (size_t)blockIdx.x * 1024 + (size_t)threadIdx.x * 4;
  int row = (int)(i / cols);
  if (row < srcRows){
    fx4 v = *(const fx4*)(src + i);
    dst[i] = f2b(v[0]); dst[i+1] = f2b(v[1]); dst[i+2] = f2b(v[2]); dst[i+3] = f2b(v[3]);
  } else {
    dst[i] = 0; dst[i+1] = 0; dst[i+2] = 0; dst[i+3] = 0;
  }
}

__global__ void k_xcat(const float* __restrict__ x, const float* __restrict__ ad,
                       u16* __restrict__ dst){
  size_t i = (size_t)blockIdx.x * 1024 + (size_t)threadIdx.x * 4;
  int row = (int)(i >> 12);
  int col = (int)(i & 4095);
  const float* s = nullptr;
  if (row < 4096) s = x + i;
  else if (row < 4096 + Bz*ALz) s = ad + (size_t)(row - 4096) * DIMz + col;
  if (s){
    fx4 v = *(const fx4*)s;
    dst[i] = f2b(v[0]); dst[i+1] = f2b(v[1]); dst[i+2] = f2b(v[2]); dst[i+3] = f2b(v[3]);
  } else {
    dst[i] = 0; dst[i+1] = 0; dst[i+2] = 0; dst[i+3] = 0;
  }
}

__global__ void k_l1cat(const float* __restrict__ a, const float* __restrict__ b,
                        const float* __restrict__ c, u16* __restrict__ dst){
  size_t i = (size_t)blockIdx.x * 1024 + (size_t)threadIdx.x * 4;
  int row = (int)(i >> 12);
  int col = (int)(i & 4095);
  const float* s = nullptr;
  if (row < 16) s = a + (size_t)row * 4096 + col;
  else if (row < 32) s = b + (size_t)(row - 16) * 4096 + col;
  else if (row < 48) s = c + (size_t)(row - 32) * 4096 + col;
  if (s){
    fx4 v = *(const fx4*)s;
    dst[i] = f2b(v[0]); dst[i+1] = f2b(v[1]); dst[i+2] = f2b(v[2]); dst[i+3] = f2b(v[3]);
  } else {
    dst[i] = 0; dst[i+1] = 0; dst[i+2] = 0; dst[i+3] = 0;
  }
}

// ---------- 256x256 8-phase counted-vmcnt NT bf16 GEMM (m201 port) ----------
// C[m][n] = sum_k A[m][k]*B[n][k].  M,N mult of 256; K mult of 128.
// LDS 2buf x {A0,A1,B0,B1} halves of 128x64. 8 waves (2M x 4N), each owns 128x64 of C.
// Per phase: ds_read frags + stage ONE half-tile + s_barrier + 16 MFMA + s_barrier.
// vmcnt(4) only at phases 4/8 (2 half-tiles stay in flight). Final iter ph4: vmcnt(0).
#define PHASE(BUF, P, STAGE_STMT, VM_STMT)                                          \
  {                                                                                 \
    if ((P) == 0){                                                                  \
      _Pragma("unroll")                                                             \
      for (int nj = 0; nj < 4; nj++)                                                \
        _Pragma("unroll")                                                           \
        for (int kk = 0; kk < 2; kk++)                                              \
          bf[nj][kk] = *ldsRd(&lds[BUF][2 + (wn >> 1)][0][0], 128,                  \
                              (wn & 1) * 64 + nj * 16 + lrow, kk * 32 + lgrp * 8);  \
    }                                                                               \
    short8 af[2][2];                                                                \
    _Pragma("unroll")                                                               \
    for (int m2 = 0; m2 < 2; m2++)                                                  \
      _Pragma("unroll")                                                             \
      for (int kk = 0; kk < 2; kk++)                                                \
        af[m2][kk] = *ldsRd(&lds[BUF][wm][0][0], 128,                               \
                            ((P) * 2 + m2) * 16 + lrow, kk * 32 + lgrp * 8);        \
    STAGE_STMT;                                                                     \
    bar();                                                                          \
    __builtin_amdgcn_s_setprio(1);                                                  \
    _Pragma("unroll")                                                               \
    for (int m2 = 0; m2 < 2; m2++)                                                  \
      _Pragma("unroll")                                                             \
      for (int nj = 0; nj < 4; nj++)                                                \
        _Pragma("unroll")                                                           \
        for (int kk = 0; kk < 2; kk++)                                              \
          acc[(P) * 2 + m2][nj] = __builtin_amdgcn_mfma_f32_16x16x32_bf16(          \
              af[m2][kk], bf[nj][kk], acc[(P) * 2 + m2][nj], 0, 0, 0);              \
    __builtin_amdgcn_s_setprio(0);                                                  \
    VM_STMT;                                                                        \
    bar();                                                                          \
  }

__global__ __launch_bounds__(512, 2)
void gemm_nt256(const u16* __restrict__ A, const u16* __restrict__ Bm,
                void* __restrict__ Cp, int N, int K, int outBf16, int nbx){
  __shared__ __align__(16) u16 lds[2][4][128][64];
  const int tid = threadIdx.x;
  const int l = tid & 63, w = tid >> 6;
  const int lrow = l & 15, lgrp = l >> 4;
  const int wm = w >> 2, wn = w & 3;

  const int nwg = gridDim.x;
  const int cpx = nwg >> 3;
  const int swz = (blockIdx.x & 7) * cpx + (blockIdx.x >> 3);
  const int by = swz / nbx, bx = swz - by * nbx;
  const int bm = by << 8, bn = bx << 8;

  const u16* A0s = A  + (size_t)bm * K;
  const u16* A1s = A0s + (size_t)128 * K;
  const u16* B0s = Bm + (size_t)bn * K;
  const u16* B1s = B0s + (size_t)128 * K;
  const int nt = K >> 6;           // even, >= 2

  const fx4 fz = {0.f, 0.f, 0.f, 0.f};
  fx4 acc[8][4];
#pragma unroll
  for (int i = 0; i < 8; i++)
#pragma unroll
    for (int j = 0; j < 4; j++) acc[i][j] = fz;

  auto STAGEH = [&](int buf, int reg, const u16* src, int t){
#pragma unroll
    for (int r = 0; r < 2; r++){
      int c = r * 512 + tid;                 // 0..1023
      int row = c >> 3, cs = c & 7;
      int off = (cs ^ (row & 7)) << 3;       // pre-swizzled source, linear LDS dest
      gload16(src + (size_t)row * K + t * 64 + off, &lds[buf][reg][0][0] + c * 8);
    }
  };

  // prologue: tile0 (all 4 halves) -> buf0; B(1) -> buf1.B.  12 instr; keep B(1) in flight.
  STAGEH(0, 0, A0s, 0); STAGEH(0, 1, A1s, 0);
  STAGEH(0, 2, B0s, 0); STAGEH(0, 3, B1s, 0);
  STAGEH(1, 2, B0s, 1); STAGEH(1, 3, B1s, 1);
  asm volatile("s_waitcnt vmcnt(4)" ::: "memory");
  bar();

  short8 bf[4][2];
  const int ni = nt >> 1;
  for (int i = 0; i < ni; i++){
    const int t0 = 2 * i, t1 = 2 * i + 1;
    const bool more = (i < ni - 1);
    // phases 1-4: tile t0 from buf0
    PHASE(0, 0, { STAGEH(1, 0, A0s, t1); }, {});
    PHASE(0, 1, { STAGEH(1, 1, A1s, t1); }, {});
    PHASE(0, 2, { if (more) STAGEH(0, 2, B0s, t0 + 2); }, {});
    PHASE(0, 3, { if (more) STAGEH(0, 3, B1s, t0 + 2); },
          { if (more) { asm volatile("s_waitcnt vmcnt(4)" ::: "memory"); }
            else      { asm volatile("s_waitcnt vmcnt(0)" ::: "memory"); } });
    // phases 5-8: tile t1 from buf1
    PHASE(1, 0, { if (more) STAGEH(0, 0, A0s, t0 + 2); }, {});
    PHASE(1, 1, { if (more) STAGEH(0, 1, A1s, t0 + 2); }, {});
    PHASE(1, 2, { if (more) STAGEH(1, 2, B0s, t1 + 2); }, {});
    PHASE(1, 3, { if (more) STAGEH(1, 3, B1s, t1 + 2); },
          { if (more) { asm volatile("s_waitcnt vmcnt(4)" ::: "memory"); } });
  }

  if (outBf16){
    u16* C = (u16*)Cp;
#pragma unroll
    for (int mi = 0; mi < 8; mi++)
#pragma unroll
      for (int r = 0; r < 4; r++){
        int gm = bm + wm * 128 + mi * 16 + lgrp * 4 + r;
        u16* crow = C + (size_t)gm * N + bn + wn * 64 + lrow;
#pragma unroll
        for (int nj = 0; nj < 4; nj++) crow[nj * 16] = f2b(acc[mi][nj][r]);
      }
  } else {
    float* C = (float*)Cp;
#pragma unroll
    for (int mi = 0; mi < 8; mi++)
#pragma unroll
      for (int r = 0; r < 4; r++){
        int gm = bm + wm * 128 + mi * 16 + lgrp * 4 + r;
        float* crow = C + (size_t)gm * N + bn + wn * 64 + lrow;
#pragma unroll
        for (int nj = 0; nj < 4; nj++) crow[nj * 16] = acc[mi][nj][r];
      }
  }
}

// ---------- 128x128 NT bf16 GEMM (small-N LoRA gemms) ----------
__global__ __launch_bounds__(256)
void gemm_nt(const u16* __restrict__ A, const u16* __restrict__ Bm, void* __restrict__ Cp,
             int M, int N, int K, int outBf16){
  __shared__ __align__(16) u16 As[128][64];
  __shared__ __align__(16) u16 Bs[128][64];
  const int tid = threadIdx.x;
  const int w = tid >> 6, l = tid & 63;
  const int lrow = l & 15, lgrp = l >> 4;
  const int bm = blockIdx.y * 128, bn = blockIdx.x * 128;
  const int wr = (w >> 1) * 64, wc = (w & 1) * 64;

  const fx4 fz = {0.f, 0.f, 0.f, 0.f};
  fx4 acc[4][4];
#pragma unroll
  for (int i = 0; i < 4; i++)
#pragma unroll
    for (int j = 0; j < 4; j++) acc[i][j] = fz;

  const u16* Abase = A + (size_t)bm * K;
  const u16* Bbase = Bm + (size_t)bn * K;

  for (int k0 = 0; k0 < K; k0 += 64){
    __syncthreads();
#pragma unroll
    for (int i = 0; i < 4; i++){
      int c = i * 256 + tid;
      int row = c >> 3, cs = c & 7;
      int off = (cs ^ (row & 7)) << 3;
      gload16(Abase + (size_t)row * K + k0 + off, ((u16*)As) + c * 8);
      gload16(Bbase + (size_t)row * K + k0 + off, ((u16*)Bs) + c * 8);
    }
    __syncthreads();
#pragma unroll
    for (int kk = 0; kk < 2; kk++){
      short8 a[4], b[4];
#pragma unroll
      for (int i = 0; i < 4; i++) a[i] = *ldsRd(&As[0][0], 128, wr + i*16 + lrow, kk*32 + lgrp*8);
#pragma unroll
      for (int j = 0; j < 4; j++) b[j] = *ldsRd(&Bs[0][0], 128, wc + j*16 + lrow, kk*32 + lgrp*8);
#pragma unroll
      for (int i = 0; i < 4; i++)
#pragma unroll
        for (int j = 0; j < 4; j++)
          acc[i][j] = __builtin_amdgcn_mfma_f32_16x16x32_bf16(a[i], b[j], acc[i][j], 0, 0, 0);
    }
  }

  if (outBf16){
    u16* C = (u16*)Cp;
#pragma unroll
    for (int i = 0; i < 4; i++)
#pragma unroll
      for (int r = 0; r < 4; r++){
        int gm = bm + wr + i*16 + lgrp*4 + r;
        u16* crow = C + (size_t)gm * N + bn + wc + lrow;
#pragma unroll
        for (int j = 0; j < 4; j++) crow[j*16] = f2b(acc[i][j][r]);
      }
  } else {
    float* C = (float*)Cp;
#pragma unroll
    for (int i = 0; i < 4; i++)
#pragma unroll
      for (int r = 0; r < 4; r++){
        int gm = bm + wr + i*16 + lgrp*4 + r;
        float* crow = C + (size_t)gm * N + bn + wc + lrow;
#pragma unroll
        for (int j = 0; j < 4; j++) crow[j*16] = acc[i][j][r];
      }
  }
}

// ---------- LoRA rank-16 add ----------
__global__ void k_lora_add_b(u16* __restrict__ y, const float* __restrict__ t,
                             const float* __restrict__ l2, int roff){
  int o = blockIdx.x * 256 + threadIdx.x;
  int m = blockIdx.y;
  const fx4* tv = (const fx4*)(t + (size_t)m * 128 + roff);
  const fx4* lv = (const fx4*)(l2 + (size_t)o * 16);
  float s = 0.f;
#pragma unroll
  for (int r = 0; r < 4; r++){
    fx4 a = tv[r], b = lv[r];
    s += a[0]*b[0] + a[1]*b[1] + a[2]*b[2] + a[3]*b[3];
  }
  size_t idx = (size_t)m * DIMz + o;
  y[idx] = f2b(b2f(y[idx]) + s);
}

__global__ void k_lora_add_f(float* __restrict__ y, const float* __restrict__ t,
                             const float* __restrict__ l2, int roff){
  int o = blockIdx.x * 256 + threadIdx.x;
  int m = blockIdx.y;
  const fx4* tv = (const fx4*)(t + (size_t)m * 128 + roff);
  const fx4* lv = (const fx4*)(l2 + (size_t)o * 16);
  float s = 0.f;
#pragma unroll
  for (int r = 0; r < 4; r++){
    fx4 a = tv[r], b = lv[r];
    s += a[0]*b[0] + a[1]*b[1] + a[2]*b[2] + a[3]*b[3];
  }
  y[(size_t)m * DIMz + o] += s;
}

// ---------- RoPE + (B,S,DIM)->(B,H,S,HD) ----------
__global__ void k_rope(const u16* __restrict__ x, u16* __restrict__ out,
                       const float* __restrict__ fcos, const float* __restrict__ fsin){
  int m = blockIdx.x;
  int b = m >> 10, s = m & 1023;
#pragma unroll
  for (int i = 0; i < 8; i++){
    int p = i * 256 + threadIdx.x;
    int h = p >> 6, j = p & 63;
    size_t xi = (size_t)m * DIMz + h * HDz + 2 * j;
    float r = b2f(x[xi]), im = b2f(x[xi + 1]);
    float c = fcos[s * 64 + j], sn = fsin[s * 64 + j];
    size_t oi = (((size_t)b * Hz + h) * Sz + s) * HDz + 2 * j;
    out[oi]     = f2b(r * c - im * sn);
    out[oi + 1] = f2b(r * sn + im * c);
  }
}

// ---------- V: (B,S,H,HD) -> Vt (B,H,HD,S) ----------
__global__ void k_vtrans(const u16* __restrict__ x, u16* __restrict__ vt){
  __shared__ __align__(16) u16 tile[64][128];
  int bh = blockIdx.y;
  int b = bh >> 5, h = bh & 31;
  int s0 = blockIdx.x * 64;
  int tid = threadIdx.x;
#pragma unroll
  for (int i = 0; i < 4; i++){
    int c = i * 256 + tid;
    int ss = c >> 4, d8 = (c & 15) << 3;
    *(short8*)&tile[ss][d8] =
      *(const short8*)&x[(size_t)(b * Sz + s0 + ss) * DIMz + h * HDz + d8];
  }
  __syncthreads();
#pragma unroll
  for (int i = 0; i < 4; i++){
    int c = i * 256 + tid;
    int d = c >> 3, s8 = (c & 7) << 3;
    short8 v;
#pragma unroll
    for (int k = 0; k < 8; k++) v[k] = (short)tile[s8 + k][d];
    *(short8*)&vt[((size_t)bh * HDz + d) * Sz + s0 + s8] = v;
  }
}

// ---------- adapter K/V reshape ----------
__global__ void k_adresh(const u16* __restrict__ akf, const u16* __restrict__ avf,
                         u16* __restrict__ AK, u16* __restrict__ AVt){
  int bh = blockIdx.x;
  int b = bh >> 5, h = bh & 31;
  int tid = threadIdx.x;
#pragma unroll
  for (int i = 0; i < 8; i++){
    int e = i * 256 + tid;
    int jj = e >> 7, d = e & 127;
    u16 v = (jj < ALz) ? akf[(size_t)(b * ALz + jj) * DIMz + h * HDz + d] : (u16)0;
    AK[((size_t)bh * 16 + jj) * HDz + d] = v;
  }
#pragma unroll
  for (int i = 0; i < 16; i++){
    int e = i * 256 + tid;
    int d = e >> 5, jj = e & 31;
    u16 v = (jj < ALz) ? avf[(size_t)(b * ALz + jj) * DIMz + h * HDz + d] : (u16)0;
    AVt[((size_t)bh * HDz + d) * 32 + jj] = v;
  }
}

// ---------- flash attention + gated adapter attention ----------
__global__ __launch_bounds__(256)
void k_attn(const u16* __restrict__ Q, const u16* __restrict__ Kg,
            const u16* __restrict__ Vt, const u16* __restrict__ AKg,
            const u16* __restrict__ AVg, const float* __restrict__ gate,
            u16* __restrict__ outp){
  __shared__ __align__(16) u16 Ks[64][128];
  __shared__ __align__(16) u16 Vs[128][64];
  __shared__ __align__(16) u16 Ps[4][16][64];

  const int bh = blockIdx.y;
  const int b = bh >> 5, h = bh & 31;
  const int q0 = blockIdx.x * 64;
  const int tid = threadIdx.x;
  const int w = tid >> 6, l = tid & 63;
  const int lrow = l & 15, lgrp = l >> 4;

  const u16* Qb = Q  + (size_t)bh * (Sz * HDz) + (size_t)q0 * HDz;
  const u16* Kb = Kg + (size_t)bh * (Sz * HDz);
  const u16* Vb = Vt + (size_t)bh * (HDz * Sz);
  u16* PsB = &Ps[0][0][0];

  short8 aq[4];
#pragma unroll
  for (int kk = 0; kk < 4; kk++)
    aq[kk] = *(const short8*)&Qb[(size_t)(w*16 + lrow) * HDz + kk*32 + lgrp*8];

  const fx4 fz = {0.f, 0.f, 0.f, 0.f};
  fx4 o[8];
#pragma unroll
  for (int i = 0; i < 8; i++) o[i] = fz;
  float mrow[4], lsum[4];
#pragma unroll
  for (int r = 0; r < 4; r++){ mrow[r] = -1e30f; lsum[r] = 0.f; }

  const float scale = 0.088388347648318447f; // 1/sqrt(128)
  const int qrowbase = q0 + w * 16 + lgrp * 4;
  const int ktiles = blockIdx.x + 1;

  for (int kt = 0; kt < ktiles; kt++){
    const int k0 = kt * 64;
    __syncthreads();
#pragma unroll
    for (int i = 0; i < 4; i++){
      int c = i * 256 + tid;
      int row = c >> 4, cs = c & 15;
      int gcs = cs ^ (row & 7);
      gload16(Kb + (size_t)(k0 + row) * HDz + gcs * 8, ((u16*)Ks) + c * 8);
    }
#pragma unroll
    for (int i = 0; i < 4; i++){
      int c = i * 256 + tid;
      int row = c >> 3, cs = c & 7;
      int gcs = cs ^ (row & 7);
      gload16(Vb + (size_t)row * Sz + k0 + gcs * 8, ((u16*)Vs) + c * 8);
    }
    __syncthreads();

    fx4 sc[4];
#pragma unroll
    for (int j = 0; j < 4; j++) sc[j] = fz;
#pragma unroll
    for (int kk = 0; kk < 4; kk++){
#pragma unroll
      for (int j = 0; j < 4; j++){
        short8 bk = *ldsRd(&Ks[0][0], 256, j*16 + lrow, kk*32 + lgrp*8);
        sc[j] = __builtin_amdgcn_mfma_f32_16x16x32_bf16(aq[kk], bk, sc[j], 0, 0, 0);
      }
    }
    const int last = (kt == ktiles - 1);
    float tm[4];
#pragma unroll
    for (int r = 0; r < 4; r++){
      float mx = -1e30f;
#pragma unroll
      for (int j = 0; j < 4; j++){
        float v = sc[j][r] * scale;
        if (last){
          int kcol = k0 + j*16 + lrow;
          if (kcol > qrowbase + r) v = -1e30f;
        }
        sc[j][r] = v;
        mx = fmaxf(mx, v);
      }
#pragma unroll
      for (int d = 1; d < 16; d <<= 1) mx = fmaxf(mx, __shfl_xor(mx, d));
      tm[r] = mx;
    }
    float esc[4];
#pragma unroll
    for (int r = 0; r < 4; r++){
      float nm = fmaxf(mrow[r], tm[r]);
      esc[r] = __expf(mrow[r] - nm);
      mrow[r] = nm;
      float s = 0.f;
#pragma unroll
      for (int j = 0; j < 4; j++){
        float p = __expf(sc[j][r] - nm);
        sc[j][r] = p;
        s += p;
      }
#pragma unroll
      for (int d = 1; d < 16; d <<= 1) s += __shfl_xor(s, d);
      lsum[r] = lsum[r] * esc[r] + s;
    }
#pragma unroll
    for (int j = 0; j < 8; j++)
#pragma unroll
      for (int r = 0; r < 4; r++) o[j][r] *= esc[r];
#pragma unroll
    for (int j = 0; j < 4; j++)
#pragma unroll
      for (int r = 0; r < 4; r++)
        *psPtr(PsB, w, lgrp*4 + r, j*16 + lrow) = f2b(sc[j][r]);
#pragma unroll
    for (int kk = 0; kk < 2; kk++){
      short8 ap = *(const short8*)psPtr(PsB, w, lrow, kk*32 + lgrp*8);
#pragma unroll
      for (int j = 0; j < 8; j++){
        short8 bv = *ldsRd(&Vs[0][0], 128, j*16 + lrow, kk*32 + lgrp*8);
        o[j] = __builtin_amdgcn_mfma_f32_16x16x32_bf16(ap, bv, o[j], 0, 0, 0);
      }
    }
  }

#pragma unroll
  for (int j = 0; j < 8; j++)
#pragma unroll
    for (int r = 0; r < 4; r++) o[j][r] /= lsum[r];

  fx4 s2 = fz;
  const u16* AKb = AKg + (size_t)bh * (16 * HDz);
#pragma unroll
  for (int kk = 0; kk < 4; kk++){
    short8 bk = *(const short8*)&AKb[(size_t)lrow * HDz + kk*32 + lgrp*8];
    s2 = __builtin_amdgcn_mfma_f32_16x16x32_bf16(aq[kk], bk, s2, 0, 0, 0);
  }
  const float g = tanhf(gate[h]);
#pragma unroll
  for (int r = 0; r < 4; r++){
    float v = s2[r] * scale;
    if (lrow >= ALz) v = -1e30f;
    float mx = v;
#pragma unroll
    for (int d = 1; d < 16; d <<= 1) mx = fmaxf(mx, __shfl_xor(mx, d));
    float p = __expf(v - mx);
    float s = p;
#pragma unroll
    for (int d = 1; d < 16; d <<= 1) s += __shfl_xor(s, d);
    float p2 = g * p / s;
    *psPtr(PsB, w, lgrp*4 + r, lrow) = f2b(p2);
    *psPtr(PsB, w, lgrp*4 + r, 16 + lrow) = 0;
  }
  {
    const u16* AVb = AVg + (size_t)bh * (HDz * 32);
    short8 ap = *(const short8*)psPtr(PsB, w, lrow, lgrp*8);
#pragma unroll
    for (int j = 0; j < 8; j++){
      short8 bv = *(const short8*)&AVb[(size_t)(j*16 + lrow) * 32 + lgrp*8];
      o[j] = __builtin_amdgcn_mfma_f32_16x16x32_bf16(ap, bv, o[j], 0, 0, 0);
    }
  }

  u16* ob = outp + (size_t)(b * Sz + q0) * DIMz + h * HDz;
#pragma unroll
  for (int j = 0; j < 8; j++)
#pragma unroll
    for (int r = 0; r < 4; r++){
      int row = w*16 + lgrp*4 + r;
      ob[(size_t)row * DIMz + j*16 + lrow] = f2b(o[j][r]);
    }
}

// ---------- host ----------
extern "C" void kernel_launch(void* const* d_in, const int* in_sizes, int n_in,
                              void* d_out, int out_size, void* d_ws, size_t ws_size,
                              hipStream_t stream){
  const float* x    = (const float*)d_in[0];
  const float* adap = (const float*)d_in[1];
  const float* wq   = (const float*)d_in[2];
  const float* wk   = (const float*)d_in[3];
  const float* wv   = (const float*)d_in[4];
  const float* wo   = (const float*)d_in[5];
  const float* lq1  = (const float*)d_in[6];
  const float* lq2  = (const float*)d_in[7];
  const float* lk1  = (const float*)d_in[8];
  const float* lk2  = (const float*)d_in[9];
  const float* lv1  = (const float*)d_in[10];
  const float* lv2  = (const float*)d_in[11];
  const float* lo1  = (const float*)d_in[12];
  const float* lo2  = (const float*)d_in[13];
  const float* gate = (const float*)d_in[14];
  const float* fcos = (const float*)d_in[15];
  const float* fsin = (const float*)d_in[16];

  const size_t MB = 1024 * 1024;
  char* ws = (char*)d_ws;
  u16*  Xcat = (u16*)(ws);                 // 4352x4096 bf16 (34 MB); later Q
  u16*  Wb   = (u16*)(ws + 34 * MB);       // 32 MB; later K
  u16*  xq   = (u16*)(ws + 66 * MB);       // 34 MB; later attn_out
  u16*  xk   = (u16*)(ws + 100 * MB);      // 34 MB
  u16*  xv   = (u16*)(ws + 134 * MB);      // 34 MB
  u16*  Vt   = (u16*)(ws + 168 * MB);      // 32 MB; t (f32) aliases (disjoint lifetimes)
  float* t   = (float*)(ws + 168 * MB);
  u16*  l1b  = (u16*)(ws + 200 * MB);      // 1 MB
  u16*  AKb  = (u16*)(ws + 201 * MB);      // 0.5 MB
  u16*  AVb  = (u16*)(ws + 201 * MB + 512 * 1024); // 1 MB
  u16*  Qb = Xcat;
  u16*  Kb = Wb;
  u16*  attn = xq;
  float* out = (float*)d_out;

  dim3 blk(256);
  const int MCAT = 4352;  // 4096 + 40 adapter rows, padded to x256

  k_xcat<<<dim3(MCAT * 4096 / 1024), blk, 0, stream>>>(x, adap, Xcat);

  // Q/K/V projections: 8-phase 256^2 GEMM (grid 17x16=272, %8==0)
  k_f2b_pad<<<dim3(4096 * 4096 / 1024), blk, 0, stream>>>(wq, Wb, 4096, 4096, 4096);
  gemm_nt256<<<dim3(272), dim3(512), 0, stream>>>(Xcat, Wb, xq, 4096, 4096, 1, 16);
  k_f2b_pad<<<dim3(4096 * 4096 / 1024), blk, 0, stream>>>(wk, Wb, 4096, 4096, 4096);
  gemm_nt256<<<dim3(272), dim3(512), 0, stream>>>(Xcat, Wb, xk, 4096, 4096, 1, 16);
  k_f2b_pad<<<dim3(4096 * 4096 / 1024), blk, 0, stream>>>(wv, Wb, 4096, 4096, 4096);
  gemm_nt256<<<dim3(272), dim3(512), 0, stream>>>(Xcat, Wb, xv, 4096, 4096, 1, 16);

  // LoRA l1 (q,k,v concatenated, N=128): small 128^2 kernel
  k_l1cat<<<dim3(128 * 4096 / 1024), blk, 0, stream>>>(lq1, lk1, lv1, l1b);
  gemm_nt<<<dim3(1, 33), blk, 0, stream>>>(Xcat, l1b, t, 4224, 128, 4096, 0);
  k_lora_add_b<<<dim3(16, 4096), blk, 0, stream>>>(xq, t, lq2, 0);
  k_lora_add_b<<<dim3(16, 4096), blk, 0, stream>>>(xk, t, lk2, 16);
  k_lora_add_b<<<dim3(16, 4096), blk, 0, stream>>>(xv, t, lv2, 32);

  k_rope<<<dim3(4096), blk, 0, stream>>>(xq, Qb, fcos, fsin);
  k_rope<<<dim3(4096), blk, 0, stream>>>(xk, Kb, fcos, fsin);
  k_vtrans<<<dim3(16, 128), blk, 0, stream>>>(xv, Vt);
  k_adresh<<<dim3(128), blk, 0, stream>>>(xk + (size_t)4096 * 4096,
                                          xv + (size_t)4096 * 4096, AKb, AVb);

  k_attn<<<dim3(16, 128), blk, 0, stream>>>(Qb, Kb, Vt, AKb, AVb, gate, attn);

  // output projection (grid 16x16=256) + LoRA
  k_f2b_pad<<<dim3(4096 * 4096 / 1024), blk, 0, stream>>>(wo, Wb, 4096, 4096, 4096);
  gemm_nt256<<<dim3(256), dim3(512), 0, stream>>>(attn, Wb, out, 4096, 4096, 0, 16);
  k_f2b_pad<<<dim3(128 * 4096 / 1024), blk, 0, stream>>>(lo1, l1b, 16, 4096, 128);
  gemm_nt<<<dim3(1, 32), blk, 0, stream>>>(attn, l1b, t, 4096, 128, 4096, 0);
  k_lora_add_f<<<dim3(16, 4096), blk, 0, stream>>>(out, t, lo2, 0);
}

// Round 7
// 1298.452 us; speedup vs baseline: 1.1946x; 1.1208x over previous
//
#include <hip/hip_runtime.h>
#include <stdint.h>

#define Bz 4
#define Sz 1024
#define DIMz 4096
#define Hz 32
#define HDz 128
#define ALz 10

typedef unsigned short u16;
typedef __attribute__((ext_vector_type(8))) short short8;
typedef __attribute__((ext_vector_type(4))) float fx4;

__device__ __forceinline__ u16 f2b(float f){
  union { float f; unsigned u; } v; v.f = f;
  unsigned r = v.u + 0x7FFFu + ((v.u >> 16) & 1u);
  return (u16)(r >> 16);
}
__device__ __forceinline__ float b2f(u16 h){
  union { unsigned u; float f; } v; v.u = ((unsigned)h) << 16; return v.f;
}
__device__ __forceinline__ void gload16(const void* g, void* l){
  __builtin_amdgcn_global_load_lds(
    (const __attribute__((address_space(1))) uint32_t*)g,
    (__attribute__((address_space(3))) uint32_t*)l, 16, 0, 0);
}
__device__ __forceinline__ void bar(){
  asm volatile("" ::: "memory");
  __builtin_amdgcn_s_barrier();
  asm volatile("" ::: "memory");
}

// ---------- LDS swizzle helper (T2: byte ^= (row&7)<<4) ----------
__device__ __forceinline__ const short8* ldsRd(const u16* base, int rowBytes, int row, int colElem){
  unsigned byte = (unsigned)(row * rowBytes + colElem * 2);
  byte ^= (unsigned)((row & 7) << 4);
  return (const short8*)((const char*)base + byte);
}
__device__ __forceinline__ u16* psPtr(u16* base, int w, int row, int colElem){
  unsigned byte = (unsigned)(row * 128 + colElem * 2);
  byte ^= (unsigned)((row & 7) << 4);
  return (u16*)((char*)base + w * 2048 + byte);
}

// ---------- conversions ----------
__global__ void k_f2b_pad(const float* __restrict__ src, u16* __restrict__ dst,
                          int srcRows, int cols, int dstRows){
  size_t i = (size_t)blockIdx.x * 1024 + (size_t)threadIdx.x * 4;
  int row = (int)(i / cols);
  if (row < srcRows){
    fx4 v = *(const fx4*)(src + i);
    dst[i] = f2b(v[0]); dst[i+1] = f2b(v[1]); dst[i+2] = f2b(v[2]); dst[i+3] = f2b(v[3]);
  } else {
    dst[i] = 0; dst[i+1] = 0; dst[i+2] = 0; dst[i+3] = 0;
  }
}

__global__ void k_xcat(const float* __restrict__ x, const float* __restrict__ ad,
                       u16* __restrict__ dst){
  size_t i = (size_t)blockIdx.x * 1024 + (size_t)threadIdx.x * 4;
  int row = (int)(i >> 12);
  int col = (int)(i & 4095);
  const float* s = nullptr;
  if (row < 4096) s = x + i;
  else if (row < 4096 + Bz*ALz) s = ad + (size_t)(row - 4096) * DIMz + col;
  if (s){
    fx4 v = *(const fx4*)s;
    dst[i] = f2b(v[0]); dst[i+1] = f2b(v[1]); dst[i+2] = f2b(v[2]); dst[i+3] = f2b(v[3]);
  } else {
    dst[i] = 0; dst[i+1] = 0; dst[i+2] = 0; dst[i+3] = 0;
  }
}

__global__ void k_l1cat(const float* __restrict__ a, const float* __restrict__ b,
                        const float* __restrict__ c, u16* __restrict__ dst){
  size_t i = (size_t)blockIdx.x * 1024 + (size_t)threadIdx.x * 4;
  int row = (int)(i >> 12);
  int col = (int)(i & 4095);
  const float* s = nullptr;
  if (row < 16) s = a + (size_t)row * 4096 + col;
  else if (row < 32) s = b + (size_t)(row - 16) * 4096 + col;
  else if (row < 48) s = c + (size_t)(row - 32) * 4096 + col;
  if (s){
    fx4 v = *(const fx4*)s;
    dst[i] = f2b(v[0]); dst[i+1] = f2b(v[1]); dst[i+2] = f2b(v[2]); dst[i+3] = f2b(v[3]);
  } else {
    dst[i] = 0; dst[i+1] = 0; dst[i+2] = 0; dst[i+3] = 0;
  }
}

// ---------- 256x256 8-phase counted-vmcnt NT bf16 GEMM ----------
#define PHASE(BUF, P, STAGE_STMT, VM_STMT)                                          \
  {                                                                                 \
    if ((P) == 0){                                                                  \
      _Pragma("unroll")                                                             \
      for (int nj = 0; nj < 4; nj++)                                                \
        _Pragma("unroll")                                                           \
        for (int kk = 0; kk < 2; kk++)                                              \
          bf[nj][kk] = *ldsRd(&lds[BUF][2 + (wn >> 1)][0][0], 128,                  \
                              (wn & 1) * 64 + nj * 16 + lrow, kk * 32 + lgrp * 8);  \
    }                                                                               \
    short8 af[2][2];                                                                \
    _Pragma("unroll")                                                               \
    for (int m2 = 0; m2 < 2; m2++)                                                  \
      _Pragma("unroll")                                                             \
      for (int kk = 0; kk < 2; kk++)                                                \
        af[m2][kk] = *ldsRd(&lds[BUF][wm][0][0], 128,                               \
                            ((P) * 2 + m2) * 16 + lrow, kk * 32 + lgrp * 8);        \
    STAGE_STMT;                                                                     \
    bar();                                                                          \
    __builtin_amdgcn_s_setprio(1);                                                  \
    _Pragma("unroll")                                                               \
    for (int m2 = 0; m2 < 2; m2++)                                                  \
      _Pragma("unroll")                                                             \
      for (int nj = 0; nj < 4; nj++)                                                \
        _Pragma("unroll")                                                           \
        for (int kk = 0; kk < 2; kk++)                                              \
          acc[(P) * 2 + m2][nj] = __builtin_amdgcn_mfma_f32_16x16x32_bf16(          \
              af[m2][kk], bf[nj][kk], acc[(P) * 2 + m2][nj], 0, 0, 0);              \
    __builtin_amdgcn_s_setprio(0);                                                  \
    VM_STMT;                                                                        \
    bar();                                                                          \
  }

__global__ __launch_bounds__(512, 2)
void gemm_nt256(const u16* __restrict__ A, const u16* __restrict__ Bm,
                void* __restrict__ Cp, int N, int K, int outBf16, int nbx){
  __shared__ __align__(16) u16 lds[2][4][128][64];
  const int tid = threadIdx.x;
  const int l = tid & 63, w = tid >> 6;
  const int lrow = l & 15, lgrp = l >> 4;
  const int wm = w >> 2, wn = w & 3;

  const int nwg = gridDim.x;
  const int cpx = nwg >> 3;
  const int swz = (blockIdx.x & 7) * cpx + (blockIdx.x >> 3);
  const int by = swz / nbx, bx = swz - by * nbx;
  const int bm = by << 8, bn = bx << 8;

  const u16* A0s = A  + (size_t)bm * K;
  const u16* A1s = A0s + (size_t)128 * K;
  const u16* B0s = Bm + (size_t)bn * K;
  const u16* B1s = B0s + (size_t)128 * K;
  const int nt = K >> 6;           // even, >= 2

  const fx4 fz = {0.f, 0.f, 0.f, 0.f};
  fx4 acc[8][4];
#pragma unroll
  for (int i = 0; i < 8; i++)
#pragma unroll
    for (int j = 0; j < 4; j++) acc[i][j] = fz;

  auto STAGEH = [&](int buf, int reg, const u16* src, int t){
#pragma unroll
    for (int r = 0; r < 2; r++){
      int c = r * 512 + tid;
      int row = c >> 3, cs = c & 7;
      int off = (cs ^ (row & 7)) << 3;
      gload16(src + (size_t)row * K + t * 64 + off, &lds[buf][reg][0][0] + c * 8);
    }
  };

  STAGEH(0, 0, A0s, 0); STAGEH(0, 1, A1s, 0);
  STAGEH(0, 2, B0s, 0); STAGEH(0, 3, B1s, 0);
  STAGEH(1, 2, B0s, 1); STAGEH(1, 3, B1s, 1);
  asm volatile("s_waitcnt vmcnt(4)" ::: "memory");
  bar();

  short8 bf[4][2];
  const int ni = nt >> 1;
  for (int i = 0; i < ni; i++){
    const int t0 = 2 * i, t1 = 2 * i + 1;
    const bool more = (i < ni - 1);
    PHASE(0, 0, { STAGEH(1, 0, A0s, t1); }, {});
    PHASE(0, 1, { STAGEH(1, 1, A1s, t1); }, {});
    PHASE(0, 2, { if (more) STAGEH(0, 2, B0s, t0 + 2); }, {});
    PHASE(0, 3, { if (more) STAGEH(0, 3, B1s, t0 + 2); },
          { if (more) { asm volatile("s_waitcnt vmcnt(4)" ::: "memory"); }
            else      { asm volatile("s_waitcnt vmcnt(0)" ::: "memory"); } });
    PHASE(1, 0, { if (more) STAGEH(0, 0, A0s, t0 + 2); }, {});
    PHASE(1, 1, { if (more) STAGEH(0, 1, A1s, t0 + 2); }, {});
    PHASE(1, 2, { if (more) STAGEH(1, 2, B0s, t1 + 2); }, {});
    PHASE(1, 3, { if (more) STAGEH(1, 3, B1s, t1 + 2); },
          { if (more) { asm volatile("s_waitcnt vmcnt(4)" ::: "memory"); } });
  }

  if (outBf16){
    u16* C = (u16*)Cp;
#pragma unroll
    for (int mi = 0; mi < 8; mi++)
#pragma unroll
      for (int r = 0; r < 4; r++){
        int gm = bm + wm * 128 + mi * 16 + lgrp * 4 + r;
        u16* crow = C + (size_t)gm * N + bn + wn * 64 + lrow;
#pragma unroll
        for (int nj = 0; nj < 4; nj++) crow[nj * 16] = f2b(acc[mi][nj][r]);
      }
  } else {
    float* C = (float*)Cp;
#pragma unroll
    for (int mi = 0; mi < 8; mi++)
#pragma unroll
      for (int r = 0; r < 4; r++){
        int gm = bm + wm * 128 + mi * 16 + lgrp * 4 + r;
        float* crow = C + (size_t)gm * N + bn + wn * 64 + lrow;
#pragma unroll
        for (int nj = 0; nj < 4; nj++) crow[nj * 16] = acc[mi][nj][r];
      }
  }
}

// ---------- thin adapter GEMM: C[48][N] = A[48][K] * B[N][K]^T (rows 40.. are zero-pad) ----------
// grid: N/64 blocks, 256 thr (4 waves); wave w covers cols n0+w*16..+15, 3 m-frags.
__global__ __launch_bounds__(256)
void k_adgemm(const u16* __restrict__ A, const u16* __restrict__ Bm,
              u16* __restrict__ C, int N, int K){
  const int tid = threadIdx.x;
  const int w = tid >> 6, l = tid & 63;
  const int lrow = l & 15, lgrp = l >> 4;
  const int n0 = blockIdx.x * 64 + w * 16;

  const fx4 fz = {0.f, 0.f, 0.f, 0.f};
  fx4 acc[3];
#pragma unroll
  for (int i = 0; i < 3; i++) acc[i] = fz;

  const u16* Brow = Bm + (size_t)(n0 + lrow) * K + lgrp * 8;
  const u16* Arow = A + (size_t)lrow * K + lgrp * 8;
#pragma unroll 2
  for (int k0 = 0; k0 < K; k0 += 32){
    short8 b = *(const short8*)(Brow + k0);
#pragma unroll
    for (int mf = 0; mf < 3; mf++){
      short8 a = *(const short8*)(Arow + (size_t)mf * 16 * K + k0);
      acc[mf] = __builtin_amdgcn_mfma_f32_16x16x32_bf16(a, b, acc[mf], 0, 0, 0);
    }
  }
#pragma unroll
  for (int mf = 0; mf < 3; mf++)
#pragma unroll
    for (int r = 0; r < 4; r++)
      C[(size_t)(mf * 16 + lgrp * 4 + r) * N + n0 + lrow] = f2b(acc[mf][r]);
}

// ---------- 128x128 NT bf16 GEMM (small-N LoRA gemms) ----------
__global__ __launch_bounds__(256)
void gemm_nt(const u16* __restrict__ A, const u16* __restrict__ Bm, void* __restrict__ Cp,
             int M, int N, int K, int outBf16){
  __shared__ __align__(16) u16 As[128][64];
  __shared__ __align__(16) u16 Bs[128][64];
  const int tid = threadIdx.x;
  const int w = tid >> 6, l = tid & 63;
  const int lrow = l & 15, lgrp = l >> 4;
  const int bm = blockIdx.y * 128, bn = blockIdx.x * 128;
  const int wr = (w >> 1) * 64, wc = (w & 1) * 64;

  const fx4 fz = {0.f, 0.f, 0.f, 0.f};
  fx4 acc[4][4];
#pragma unroll
  for (int i = 0; i < 4; i++)
#pragma unroll
    for (int j = 0; j < 4; j++) acc[i][j] = fz;

  const u16* Abase = A + (size_t)bm * K;
  const u16* Bbase = Bm + (size_t)bn * K;

  for (int k0 = 0; k0 < K; k0 += 64){
    __syncthreads();
#pragma unroll
    for (int i = 0; i < 4; i++){
      int c = i * 256 + tid;
      int row = c >> 3, cs = c & 7;
      int off = (cs ^ (row & 7)) << 3;
      gload16(Abase + (size_t)row * K + k0 + off, ((u16*)As) + c * 8);
      gload16(Bbase + (size_t)row * K + k0 + off, ((u16*)Bs) + c * 8);
    }
    __syncthreads();
#pragma unroll
    for (int kk = 0; kk < 2; kk++){
      short8 a[4], b[4];
#pragma unroll
      for (int i = 0; i < 4; i++) a[i] = *ldsRd(&As[0][0], 128, wr + i*16 + lrow, kk*32 + lgrp*8);
#pragma unroll
      for (int j = 0; j < 4; j++) b[j] = *ldsRd(&Bs[0][0], 128, wc + j*16 + lrow, kk*32 + lgrp*8);
#pragma unroll
      for (int i = 0; i < 4; i++)
#pragma unroll
        for (int j = 0; j < 4; j++)
          acc[i][j] = __builtin_amdgcn_mfma_f32_16x16x32_bf16(a[i], b[j], acc[i][j], 0, 0, 0);
    }
  }

  if (outBf16){
    u16* C = (u16*)Cp;
#pragma unroll
    for (int i = 0; i < 4; i++)
#pragma unroll
      for (int r = 0; r < 4; r++){
        int gm = bm + wr + i*16 + lgrp*4 + r;
        u16* crow = C + (size_t)gm * N + bn + wc + lrow;
#pragma unroll
        for (int j = 0; j < 4; j++) crow[j*16] = f2b(acc[i][j][r]);
      }
  } else {
    float* C = (float*)Cp;
#pragma unroll
    for (int i = 0; i < 4; i++)
#pragma unroll
      for (int r = 0; r < 4; r++){
        int gm = bm + wr + i*16 + lgrp*4 + r;
        float* crow = C + (size_t)gm * N + bn + wc + lrow;
#pragma unroll
        for (int j = 0; j < 4; j++) crow[j*16] = acc[i][j][r];
      }
  }
}

// ---------- LoRA rank-16 add ----------
__global__ void k_lora_add_b(u16* __restrict__ y, const float* __restrict__ t,
                             const float* __restrict__ l2, int roff){
  int o = blockIdx.x * 256 + threadIdx.x;
  int m = blockIdx.y;
  const fx4* tv = (const fx4*)(t + (size_t)m * 128 + roff);
  const fx4* lv = (const fx4*)(l2 + (size_t)o * 16);
  float s = 0.f;
#pragma unroll
  for (int r = 0; r < 4; r++){
    fx4 a = tv[r], b = lv[r];
    s += a[0]*b[0] + a[1]*b[1] + a[2]*b[2] + a[3]*b[3];
  }
  size_t idx = (size_t)m * DIMz + o;
  y[idx] = f2b(b2f(y[idx]) + s);
}

__global__ void k_lora_add_f(float* __restrict__ y, const float* __restrict__ t,
                             const float* __restrict__ l2, int roff){
  int o = blockIdx.x * 256 + threadIdx.x;
  int m = blockIdx.y;
  const fx4* tv = (const fx4*)(t + (size_t)m * 128 + roff);
  const fx4* lv = (const fx4*)(l2 + (size_t)o * 16);
  float s = 0.f;
#pragma unroll
  for (int r = 0; r < 4; r++){
    fx4 a = tv[r], b = lv[r];
    s += a[0]*b[0] + a[1]*b[1] + a[2]*b[2] + a[3]*b[3];
  }
  y[(size_t)m * DIMz + o] += s;
}

// ---------- RoPE + (B,S,DIM)->(B,H,S,HD) ----------
__global__ void k_rope(const u16* __restrict__ x, u16* __restrict__ out,
                       const float* __restrict__ fcos, const float* __restrict__ fsin){
  int m = blockIdx.x;
  int b = m >> 10, s = m & 1023;
#pragma unroll
  for (int i = 0; i < 8; i++){
    int p = i * 256 + threadIdx.x;
    int h = p >> 6, j = p & 63;
    size_t xi = (size_t)m * DIMz + h * HDz + 2 * j;
    float r = b2f(x[xi]), im = b2f(x[xi + 1]);
    float c = fcos[s * 64 + j], sn = fsin[s * 64 + j];
    size_t oi = (((size_t)b * Hz + h) * Sz + s) * HDz + 2 * j;
    out[oi]     = f2b(r * c - im * sn);
    out[oi + 1] = f2b(r * sn + im * c);
  }
}

// ---------- V: (B,S,H,HD) -> Vt (B,H,HD,S) ----------
__global__ void k_vtrans(const u16* __restrict__ x, u16* __restrict__ vt){
  __shared__ __align__(16) u16 tile[64][128];
  int bh = blockIdx.y;
  int b = bh >> 5, h = bh & 31;
  int s0 = blockIdx.x * 64;
  int tid = threadIdx.x;
#pragma unroll
  for (int i = 0; i < 4; i++){
    int c = i * 256 + tid;
    int ss = c >> 4, d8 = (c & 15) << 3;
    *(short8*)&tile[ss][d8] =
      *(const short8*)&x[(size_t)(b * Sz + s0 + ss) * DIMz + h * HDz + d8];
  }
  __syncthreads();
#pragma unroll
  for (int i = 0; i < 4; i++){
    int c = i * 256 + tid;
    int d = c >> 3, s8 = (c & 7) << 3;
    short8 v;
#pragma unroll
    for (int k = 0; k < 8; k++) v[k] = (short)tile[s8 + k][d];
    *(short8*)&vt[((size_t)bh * HDz + d) * Sz + s0 + s8] = v;
  }
}

// ---------- adapter K/V reshape ----------
__global__ void k_adresh(const u16* __restrict__ akf, const u16* __restrict__ avf,
                         u16* __restrict__ AK, u16* __restrict__ AVt){
  int bh = blockIdx.x;
  int b = bh >> 5, h = bh & 31;
  int tid = threadIdx.x;
#pragma unroll
  for (int i = 0; i < 8; i++){
    int e = i * 256 + tid;
    int jj = e >> 7, d = e & 127;
    u16 v = (jj < ALz) ? akf[(size_t)(b * ALz + jj) * DIMz + h * HDz + d] : (u16)0;
    AK[((size_t)bh * 16 + jj) * HDz + d] = v;
  }
#pragma unroll
  for (int i = 0; i < 16; i++){
    int e = i * 256 + tid;
    int d = e >> 5, jj = e & 31;
    u16 v = (jj < ALz) ? avf[(size_t)(b * ALz + jj) * DIMz + h * HDz + d] : (u16)0;
    AVt[((size_t)bh * HDz + d) * 32 + jj] = v;
  }
}

// ---------- flash attention + gated adapter attention ----------
__global__ __launch_bounds__(256)
void k_attn(const u16* __restrict__ Q, const u16* __restrict__ Kg,
            const u16* __restrict__ Vt, const u16* __restrict__ AKg,
            const u16* __restrict__ AVg, const float* __restrict__ gate,
            u16* __restrict__ outp){
  __shared__ __align__(16) u16 Ks[64][128];
  __shared__ __align__(16) u16 Vs[128][64];
  __shared__ __align__(16) u16 Ps[4][16][64];

  const int bh = blockIdx.y;
  const int b = bh >> 5, h = bh & 31;
  const int q0 = blockIdx.x * 64;
  const int tid = threadIdx.x;
  const int w = tid >> 6, l = tid & 63;
  const int lrow = l & 15, lgrp = l >> 4;

  const u16* Qb = Q  + (size_t)bh * (Sz * HDz) + (size_t)q0 * HDz;
  const u16* Kb = Kg + (size_t)bh * (Sz * HDz);
  const u16* Vb = Vt + (size_t)bh * (HDz * Sz);
  u16* PsB = &Ps[0][0][0];

  short8 aq[4];
#pragma unroll
  for (int kk = 0; kk < 4; kk++)
    aq[kk] = *(const short8*)&Qb[(size_t)(w*16 + lrow) * HDz + kk*32 + lgrp*8];

  const fx4 fz = {0.f, 0.f, 0.f, 0.f};
  fx4 o[8];
#pragma unroll
  for (int i = 0; i < 8; i++) o[i] = fz;
  float mrow[4], lsum[4];
#pragma unroll
  for (int r = 0; r < 4; r++){ mrow[r] = -1e30f; lsum[r] = 0.f; }

  const float scale = 0.088388347648318447f; // 1/sqrt(128)
  const int qrowbase = q0 + w * 16 + lgrp * 4;
  const int ktiles = blockIdx.x + 1;

  for (int kt = 0; kt < ktiles; kt++){
    const int k0 = kt * 64;
    __syncthreads();
#pragma unroll
    for (int i = 0; i < 4; i++){
      int c = i * 256 + tid;
      int row = c >> 4, cs = c & 15;
      int gcs = cs ^ (row & 7);
      gload16(Kb + (size_t)(k0 + row) * HDz + gcs * 8, ((u16*)Ks) + c * 8);
    }
#pragma unroll
    for (int i = 0; i < 4; i++){
      int c = i * 256 + tid;
      int row = c >> 3, cs = c & 7;
      int gcs = cs ^ (row & 7);
      gload16(Vb + (size_t)row * Sz + k0 + gcs * 8, ((u16*)Vs) + c * 8);
    }
    __syncthreads();

    fx4 sc[4];
#pragma unroll
    for (int j = 0; j < 4; j++) sc[j] = fz;
#pragma unroll
    for (int kk = 0; kk < 4; kk++){
#pragma unroll
      for (int j = 0; j < 4; j++){
        short8 bk = *ldsRd(&Ks[0][0], 256, j*16 + lrow, kk*32 + lgrp*8);
        sc[j] = __builtin_amdgcn_mfma_f32_16x16x32_bf16(aq[kk], bk, sc[j], 0, 0, 0);
      }
    }
    const int last = (kt == ktiles - 1);
    float tm[4];
#pragma unroll
    for (int r = 0; r < 4; r++){
      float mx = -1e30f;
#pragma unroll
      for (int j = 0; j < 4; j++){
        float v = sc[j][r] * scale;
        if (last){
          int kcol = k0 + j*16 + lrow;
          if (kcol > qrowbase + r) v = -1e30f;
        }
        sc[j][r] = v;
        mx = fmaxf(mx, v);
      }
#pragma unroll
      for (int d = 1; d < 16; d <<= 1) mx = fmaxf(mx, __shfl_xor(mx, d));
      tm[r] = mx;
    }
    float esc[4];
#pragma unroll
    for (int r = 0; r < 4; r++){
      float nm = fmaxf(mrow[r], tm[r]);
      esc[r] = __expf(mrow[r] - nm);
      mrow[r] = nm;
      float s = 0.f;
#pragma unroll
      for (int j = 0; j < 4; j++){
        float p = __expf(sc[j][r] - nm);
        sc[j][r] = p;
        s += p;
      }
#pragma unroll
      for (int d = 1; d < 16; d <<= 1) s += __shfl_xor(s, d);
      lsum[r] = lsum[r] * esc[r] + s;
    }
#pragma unroll
    for (int j = 0; j < 8; j++)
#pragma unroll
      for (int r = 0; r < 4; r++) o[j][r] *= esc[r];
#pragma unroll
    for (int j = 0; j < 4; j++)
#pragma unroll
      for (int r = 0; r < 4; r++)
        *psPtr(PsB, w, lgrp*4 + r, j*16 + lrow) = f2b(sc[j][r]);
#pragma unroll
    for (int kk = 0; kk < 2; kk++){
      short8 ap = *(const short8*)psPtr(PsB, w, lrow, kk*32 + lgrp*8);
#pragma unroll
      for (int j = 0; j < 8; j++){
        short8 bv = *ldsRd(&Vs[0][0], 128, j*16 + lrow, kk*32 + lgrp*8);
        o[j] = __builtin_amdgcn_mfma_f32_16x16x32_bf16(ap, bv, o[j], 0, 0, 0);
      }
    }
  }

#pragma unroll
  for (int j = 0; j < 8; j++)
#pragma unroll
    for (int r = 0; r < 4; r++) o[j][r] /= lsum[r];

  fx4 s2 = fz;
  const u16* AKb = AKg + (size_t)bh * (16 * HDz);
#pragma unroll
  for (int kk = 0; kk < 4; kk++){
    short8 bk = *(const short8*)&AKb[(size_t)lrow * HDz + kk*32 + lgrp*8];
    s2 = __builtin_amdgcn_mfma_f32_16x16x32_bf16(aq[kk], bk, s2, 0, 0, 0);
  }
  const float g = tanhf(gate[h]);
#pragma unroll
  for (int r = 0; r < 4; r++){
    float v = s2[r] * scale;
    if (lrow >= ALz) v = -1e30f;
    float mx = v;
#pragma unroll
    for (int d = 1; d < 16; d <<= 1) mx = fmaxf(mx, __shfl_xor(mx, d));
    float p = __expf(v - mx);
    float s = p;
#pragma unroll
    for (int d = 1; d < 16; d <<= 1) s += __shfl_xor(s, d);
    float p2 = g * p / s;
    *psPtr(PsB, w, lgrp*4 + r, lrow) = f2b(p2);
    *psPtr(PsB, w, lgrp*4 + r, 16 + lrow) = 0;
  }
  {
    const u16* AVb = AVg + (size_t)bh * (HDz * 32);
    short8 ap = *(const short8*)psPtr(PsB, w, lrow, lgrp*8);
#pragma unroll
    for (int j = 0; j < 8; j++){
      short8 bv = *(const short8*)&AVb[(size_t)(j*16 + lrow) * 32 + lgrp*8];
      o[j] = __builtin_amdgcn_mfma_f32_16x16x32_bf16(ap, bv, o[j], 0, 0, 0);
    }
  }

  u16* ob = outp + (size_t)(b * Sz + q0) * DIMz + h * HDz;
#pragma unroll
  for (int j = 0; j < 8; j++)
#pragma unroll
    for (int r = 0; r < 4; r++){
      int row = w*16 + lgrp*4 + r;
      ob[(size_t)row * DIMz + j*16 + lrow] = f2b(o[j][r]);
    }
}

// ---------- host ----------
extern "C" void kernel_launch(void* const* d_in, const int* in_sizes, int n_in,
                              void* d_out, int out_size, void* d_ws, size_t ws_size,
                              hipStream_t stream){
  const float* x    = (const float*)d_in[0];
  const float* adap = (const float*)d_in[1];
  const float* wq   = (const float*)d_in[2];
  const float* wk   = (const float*)d_in[3];
  const float* wv   = (const float*)d_in[4];
  const float* wo   = (const float*)d_in[5];
  const float* lq1  = (const float*)d_in[6];
  const float* lq2  = (const float*)d_in[7];
  const float* lk1  = (const float*)d_in[8];
  const float* lk2  = (const float*)d_in[9];
  const float* lv1  = (const float*)d_in[10];
  const float* lv2  = (const float*)d_in[11];
  const float* lo1  = (const float*)d_in[12];
  const float* lo2  = (const float*)d_in[13];
  const float* gate = (const float*)d_in[14];
  const float* fcos = (const float*)d_in[15];
  const float* fsin = (const float*)d_in[16];

  const size_t MB = 1024 * 1024;
  char* ws = (char*)d_ws;
  u16*  Xcat = (u16*)(ws);                 // 4352x4096 bf16 (34 MB); later Q
  u16*  Wb   = (u16*)(ws + 34 * MB);       // 32 MB; later K
  u16*  xq   = (u16*)(ws + 66 * MB);       // 34 MB; later attn_out
  u16*  xk   = (u16*)(ws + 100 * MB);      // 34 MB
  u16*  xv   = (u16*)(ws + 134 * MB);      // 34 MB
  u16*  Vt   = (u16*)(ws + 168 * MB);      // 32 MB; t (f32) aliases (disjoint lifetimes)
  float* t   = (float*)(ws + 168 * MB);
  u16*  l1b  = (u16*)(ws + 200 * MB);      // 1 MB
  u16*  AKb  = (u16*)(ws + 201 * MB);      // 0.5 MB
  u16*  AVb  = (u16*)(ws + 201 * MB + 512 * 1024); // 1 MB
  u16*  Qb = Xcat;
  u16*  Kb = Wb;
  u16*  attn = xq;
  float* out = (float*)d_out;

  dim3 blk(256);
  const int MCAT = 4352;
  const u16* Xad = Xcat + (size_t)4096 * 4096;   // adapter rows (40 + zero-pad)

  k_xcat<<<dim3(MCAT * 4096 / 1024), blk, 0, stream>>>(x, adap, Xcat);

  // Q/K/V projections: M=4096 -> grid 256 (exactly 1 block/CU wave, no tail)
  k_f2b_pad<<<dim3(4096 * 4096 / 1024), blk, 0, stream>>>(wq, Wb, 4096, 4096, 4096);
  gemm_nt256<<<dim3(256), dim3(512), 0, stream>>>(Xcat, Wb, xq, 4096, 4096, 1, 16);
  k_f2b_pad<<<dim3(4096 * 4096 / 1024), blk, 0, stream>>>(wk, Wb, 4096, 4096, 4096);
  gemm_nt256<<<dim3(256), dim3(512), 0, stream>>>(Xcat, Wb, xk, 4096, 4096, 1, 16);
  k_adgemm<<<dim3(64), blk, 0, stream>>>(Xad, Wb, xk + (size_t)4096 * 4096, 4096, 4096);
  k_f2b_pad<<<dim3(4096 * 4096 / 1024), blk, 0, stream>>>(wv, Wb, 4096, 4096, 4096);
  gemm_nt256<<<dim3(256), dim3(512), 0, stream>>>(Xcat, Wb, xv, 4096, 4096, 1, 16);
  k_adgemm<<<dim3(64), blk, 0, stream>>>(Xad, Wb, xv + (size_t)4096 * 4096, 4096, 4096);

  // LoRA l1 (q,k,v concatenated, N=128) on x rows only
  k_l1cat<<<dim3(128 * 4096 / 1024), blk, 0, stream>>>(lq1, lk1, lv1, l1b);
  gemm_nt<<<dim3(1, 32), blk, 0, stream>>>(Xcat, l1b, t, 4096, 128, 4096, 0);
  k_lora_add_b<<<dim3(16, 4096), blk, 0, stream>>>(xq, t, lq2, 0);
  k_lora_add_b<<<dim3(16, 4096), blk, 0, stream>>>(xk, t, lk2, 16);
  k_lora_add_b<<<dim3(16, 4096), blk, 0, stream>>>(xv, t, lv2, 32);

  k_rope<<<dim3(4096), blk, 0, stream>>>(xq, Qb, fcos, fsin);
  k_rope<<<dim3(4096), blk, 0, stream>>>(xk, Kb, fcos, fsin);
  k_vtrans<<<dim3(16, 128), blk, 0, stream>>>(xv, Vt);
  k_adresh<<<dim3(128), blk, 0, stream>>>(xk + (size_t)4096 * 4096,
                                          xv + (size_t)4096 * 4096, AKb, AVb);

  k_attn<<<dim3(16, 128), blk, 0, stream>>>(Qb, Kb, Vt, AKb, AVb, gate, attn);

  // output projection (grid 256) + LoRA
  k_f2b_pad<<<dim3(4096 * 4096 / 1024), blk, 0, stream>>>(wo, Wb, 4096, 4096, 4096);
  gemm_nt256<<<dim3(256), dim3(512), 0, stream>>>(attn, Wb, out, 4096, 4096, 0, 16);
  k_f2b_pad<<<dim3(128 * 4096 / 1024), blk, 0, stream>>>(lo1, l1b, 16, 4096, 128);
  gemm_nt<<<dim3(1, 32), blk, 0, stream>>>(attn, l1b, t, 4096, 128, 4096, 0);
  k_lora_add_f<<<dim3(16, 4096), blk, 0, stream>>>(out, t, lo2, 0);
}

// Round 8
// 1297.797 us; speedup vs baseline: 1.1952x; 1.0005x over previous
//
#include <hip/hip_runtime.h>
#include <stdint.h>

#define Bz 4
#define Sz 1024
#define DIMz 4096
#define Hz 32
#define HDz 128
#define ALz 10

typedef unsigned short u16;
typedef __attribute__((ext_vector_type(8))) short short8;
typedef __attribute__((ext_vector_type(4))) float fx4;

__device__ __forceinline__ u16 f2b(float f){
  union { float f; unsigned u; } v; v.f = f;
  unsigned r = v.u + 0x7FFFu + ((v.u >> 16) & 1u);
  return (u16)(r >> 16);
}
__device__ __forceinline__ float b2f(u16 h){
  union { unsigned u; float f; } v; v.u = ((unsigned)h) << 16; return v.f;
}
__device__ __forceinline__ void gload16(const void* g, void* l){
  __builtin_amdgcn_global_load_lds(
    (const __attribute__((address_space(1))) uint32_t*)g,
    (__attribute__((address_space(3))) uint32_t*)l, 16, 0, 0);
}
__device__ __forceinline__ void bar(){
  asm volatile("" ::: "memory");
  __builtin_amdgcn_s_barrier();
  asm volatile("" ::: "memory");
}

// ---------- LDS swizzle helper (T2: byte ^= (row&7)<<4) ----------
__device__ __forceinline__ const short8* ldsRd(const u16* base, int rowBytes, int row, int colElem){
  unsigned byte = (unsigned)(row * rowBytes + colElem * 2);
  byte ^= (unsigned)((row & 7) << 4);
  return (const short8*)((const char*)base + byte);
}
__device__ __forceinline__ u16* psPtr(u16* base, int w, int row, int colElem){
  unsigned byte = (unsigned)(row * 128 + colElem * 2);
  byte ^= (unsigned)((row & 7) << 4);
  return (u16*)((char*)base + w * 2048 + byte);
}

// ---------- conversions ----------
__global__ void k_f2b_pad(const float* __restrict__ src, u16* __restrict__ dst,
                          int srcRows, int cols, int dstRows){
  size_t i = (size_t)blockIdx.x * 1024 + (size_t)threadIdx.x * 4;
  int row = (int)(i / cols);
  if (row < srcRows){
    fx4 v = *(const fx4*)(src + i);
    dst[i] = f2b(v[0]); dst[i+1] = f2b(v[1]); dst[i+2] = f2b(v[2]); dst[i+3] = f2b(v[3]);
  } else {
    dst[i] = 0; dst[i+1] = 0; dst[i+2] = 0; dst[i+3] = 0;
  }
}

__global__ void k_xcat(const float* __restrict__ x, const float* __restrict__ ad,
                       u16* __restrict__ dst){
  size_t i = (size_t)blockIdx.x * 1024 + (size_t)threadIdx.x * 4;
  int row = (int)(i >> 12);
  int col = (int)(i & 4095);
  const float* s = nullptr;
  if (row < 4096) s = x + i;
  else if (row < 4096 + Bz*ALz) s = ad + (size_t)(row - 4096) * DIMz + col;
  if (s){
    fx4 v = *(const fx4*)s;
    dst[i] = f2b(v[0]); dst[i+1] = f2b(v[1]); dst[i+2] = f2b(v[2]); dst[i+3] = f2b(v[3]);
  } else {
    dst[i] = 0; dst[i+1] = 0; dst[i+2] = 0; dst[i+3] = 0;
  }
}

__global__ void k_l1cat(const float* __restrict__ a, const float* __restrict__ b,
                        const float* __restrict__ c, u16* __restrict__ dst){
  size_t i = (size_t)blockIdx.x * 1024 + (size_t)threadIdx.x * 4;
  int row = (int)(i >> 12);
  int col = (int)(i & 4095);
  const float* s = nullptr;
  if (row < 16) s = a + (size_t)row * 4096 + col;
  else if (row < 32) s = b + (size_t)(row - 16) * 4096 + col;
  else if (row < 48) s = c + (size_t)(row - 32) * 4096 + col;
  if (s){
    fx4 v = *(const fx4*)s;
    dst[i] = f2b(v[0]); dst[i+1] = f2b(v[1]); dst[i+2] = f2b(v[2]); dst[i+3] = f2b(v[3]);
  } else {
    dst[i] = 0; dst[i+1] = 0; dst[i+2] = 0; dst[i+3] = 0;
  }
}

// ---------- 256x256 8-phase counted-vmcnt NT bf16 GEMM ----------
#define PHASE(BUF, P, STAGE_STMT, VM_STMT)                                          \
  {                                                                                 \
    if ((P) == 0){                                                                  \
      _Pragma("unroll")                                                             \
      for (int nj = 0; nj < 4; nj++)                                                \
        _Pragma("unroll")                                                           \
        for (int kk = 0; kk < 2; kk++)                                              \
          bf[nj][kk] = *ldsRd(&lds[BUF][2 + (wn >> 1)][0][0], 128,                  \
                              (wn & 1) * 64 + nj * 16 + lrow, kk * 32 + lgrp * 8);  \
    }                                                                               \
    short8 af[2][2];                                                                \
    _Pragma("unroll")                                                               \
    for (int m2 = 0; m2 < 2; m2++)                                                  \
      _Pragma("unroll")                                                             \
      for (int kk = 0; kk < 2; kk++)                                                \
        af[m2][kk] = *ldsRd(&lds[BUF][wm][0][0], 128,                               \
                            ((P) * 2 + m2) * 16 + lrow, kk * 32 + lgrp * 8);        \
    STAGE_STMT;                                                                     \
    bar();                                                                          \
    __builtin_amdgcn_s_setprio(1);                                                  \
    _Pragma("unroll")                                                               \
    for (int m2 = 0; m2 < 2; m2++)                                                  \
      _Pragma("unroll")                                                             \
      for (int nj = 0; nj < 4; nj++)                                                \
        _Pragma("unroll")                                                           \
        for (int kk = 0; kk < 2; kk++)                                              \
          acc[(P) * 2 + m2][nj] = __builtin_amdgcn_mfma_f32_16x16x32_bf16(          \
              af[m2][kk], bf[nj][kk], acc[(P) * 2 + m2][nj], 0, 0, 0);              \
    __builtin_amdgcn_s_setprio(0);                                                  \
    VM_STMT;                                                                        \
    bar();                                                                          \
  }

__global__ __launch_bounds__(512, 2)
void gemm_nt256(const u16* __restrict__ A, const u16* __restrict__ Bm,
                void* __restrict__ Cp, int N, int K, int outBf16, int nbx){
  __shared__ __align__(16) u16 lds[2][4][128][64];
  const int tid = threadIdx.x;
  const int l = tid & 63, w = tid >> 6;
  const int lrow = l & 15, lgrp = l >> 4;
  const int wm = w >> 2, wn = w & 3;

  const int nwg = gridDim.x;
  const int cpx = nwg >> 3;
  const int swz = (blockIdx.x & 7) * cpx + (blockIdx.x >> 3);
  const int by = swz / nbx, bx = swz - by * nbx;
  const int bm = by << 8, bn = bx << 8;

  const u16* A0s = A  + (size_t)bm * K;
  const u16* A1s = A0s + (size_t)128 * K;
  const u16* B0s = Bm + (size_t)bn * K;
  const u16* B1s = B0s + (size_t)128 * K;
  const int nt = K >> 6;

  const fx4 fz = {0.f, 0.f, 0.f, 0.f};
  fx4 acc[8][4];
#pragma unroll
  for (int i = 0; i < 8; i++)
#pragma unroll
    for (int j = 0; j < 4; j++) acc[i][j] = fz;

  auto STAGEH = [&](int buf, int reg, const u16* src, int t){
#pragma unroll
    for (int r = 0; r < 2; r++){
      int c = r * 512 + tid;
      int row = c >> 3, cs = c & 7;
      int off = (cs ^ (row & 7)) << 3;
      gload16(src + (size_t)row * K + t * 64 + off, &lds[buf][reg][0][0] + c * 8);
    }
  };

  STAGEH(0, 0, A0s, 0); STAGEH(0, 1, A1s, 0);
  STAGEH(0, 2, B0s, 0); STAGEH(0, 3, B1s, 0);
  STAGEH(1, 2, B0s, 1); STAGEH(1, 3, B1s, 1);
  asm volatile("s_waitcnt vmcnt(4)" ::: "memory");
  bar();

  short8 bf[4][2];
  const int ni = nt >> 1;
  for (int i = 0; i < ni; i++){
    const int t0 = 2 * i, t1 = 2 * i + 1;
    const bool more = (i < ni - 1);
    PHASE(0, 0, { STAGEH(1, 0, A0s, t1); }, {});
    PHASE(0, 1, { STAGEH(1, 1, A1s, t1); }, {});
    PHASE(0, 2, { if (more) STAGEH(0, 2, B0s, t0 + 2); }, {});
    PHASE(0, 3, { if (more) STAGEH(0, 3, B1s, t0 + 2); },
          { if (more) { asm volatile("s_waitcnt vmcnt(4)" ::: "memory"); }
            else      { asm volatile("s_waitcnt vmcnt(0)" ::: "memory"); } });
    PHASE(1, 0, { if (more) STAGEH(0, 0, A0s, t0 + 2); }, {});
    PHASE(1, 1, { if (more) STAGEH(0, 1, A1s, t0 + 2); }, {});
    PHASE(1, 2, { if (more) STAGEH(1, 2, B0s, t1 + 2); }, {});
    PHASE(1, 3, { if (more) STAGEH(1, 3, B1s, t1 + 2); },
          { if (more) { asm volatile("s_waitcnt vmcnt(4)" ::: "memory"); } });
  }

  if (outBf16){
    u16* C = (u16*)Cp;
#pragma unroll
    for (int mi = 0; mi < 8; mi++)
#pragma unroll
      for (int r = 0; r < 4; r++){
        int gm = bm + wm * 128 + mi * 16 + lgrp * 4 + r;
        u16* crow = C + (size_t)gm * N + bn + wn * 64 + lrow;
#pragma unroll
        for (int nj = 0; nj < 4; nj++) crow[nj * 16] = f2b(acc[mi][nj][r]);
      }
  } else {
    float* C = (float*)Cp;
#pragma unroll
    for (int mi = 0; mi < 8; mi++)
#pragma unroll
      for (int r = 0; r < 4; r++){
        int gm = bm + wm * 128 + mi * 16 + lgrp * 4 + r;
        float* crow = C + (size_t)gm * N + bn + wn * 64 + lrow;
#pragma unroll
        for (int nj = 0; nj < 4; nj++) crow[nj * 16] = acc[mi][nj][r];
      }
  }
}

// ---------- thin adapter GEMM ----------
__global__ __launch_bounds__(256)
void k_adgemm(const u16* __restrict__ A, const u16* __restrict__ Bm,
              u16* __restrict__ C, int N, int K){
  const int tid = threadIdx.x;
  const int w = tid >> 6, l = tid & 63;
  const int lrow = l & 15, lgrp = l >> 4;
  const int n0 = blockIdx.x * 64 + w * 16;

  const fx4 fz = {0.f, 0.f, 0.f, 0.f};
  fx4 acc[3];
#pragma unroll
  for (int i = 0; i < 3; i++) acc[i] = fz;

  const u16* Brow = Bm + (size_t)(n0 + lrow) * K + lgrp * 8;
  const u16* Arow = A + (size_t)lrow * K + lgrp * 8;
#pragma unroll 2
  for (int k0 = 0; k0 < K; k0 += 32){
    short8 b = *(const short8*)(Brow + k0);
#pragma unroll
    for (int mf = 0; mf < 3; mf++){
      short8 a = *(const short8*)(Arow + (size_t)mf * 16 * K + k0);
      acc[mf] = __builtin_amdgcn_mfma_f32_16x16x32_bf16(a, b, acc[mf], 0, 0, 0);
    }
  }
#pragma unroll
  for (int mf = 0; mf < 3; mf++)
#pragma unroll
    for (int r = 0; r < 4; r++)
      C[(size_t)(mf * 16 + lgrp * 4 + r) * N + n0 + lrow] = f2b(acc[mf][r]);
}

// ---------- 128x128 NT bf16 GEMM (small-N LoRA gemms) ----------
__global__ __launch_bounds__(256)
void gemm_nt(const u16* __restrict__ A, const u16* __restrict__ Bm, void* __restrict__ Cp,
             int M, int N, int K, int outBf16){
  __shared__ __align__(16) u16 As[128][64];
  __shared__ __align__(16) u16 Bs[128][64];
  const int tid = threadIdx.x;
  const int w = tid >> 6, l = tid & 63;
  const int lrow = l & 15, lgrp = l >> 4;
  const int bm = blockIdx.y * 128, bn = blockIdx.x * 128;
  const int wr = (w >> 1) * 64, wc = (w & 1) * 64;

  const fx4 fz = {0.f, 0.f, 0.f, 0.f};
  fx4 acc[4][4];
#pragma unroll
  for (int i = 0; i < 4; i++)
#pragma unroll
    for (int j = 0; j < 4; j++) acc[i][j] = fz;

  const u16* Abase = A + (size_t)bm * K;
  const u16* Bbase = Bm + (size_t)bn * K;

  for (int k0 = 0; k0 < K; k0 += 64){
    __syncthreads();
#pragma unroll
    for (int i = 0; i < 4; i++){
      int c = i * 256 + tid;
      int row = c >> 3, cs = c & 7;
      int off = (cs ^ (row & 7)) << 3;
      gload16(Abase + (size_t)row * K + k0 + off, ((u16*)As) + c * 8);
      gload16(Bbase + (size_t)row * K + k0 + off, ((u16*)Bs) + c * 8);
    }
    __syncthreads();
#pragma unroll
    for (int kk = 0; kk < 2; kk++){
      short8 a[4], b[4];
#pragma unroll
      for (int i = 0; i < 4; i++) a[i] = *ldsRd(&As[0][0], 128, wr + i*16 + lrow, kk*32 + lgrp*8);
#pragma unroll
      for (int j = 0; j < 4; j++) b[j] = *ldsRd(&Bs[0][0], 128, wc + j*16 + lrow, kk*32 + lgrp*8);
#pragma unroll
      for (int i = 0; i < 4; i++)
#pragma unroll
        for (int j = 0; j < 4; j++)
          acc[i][j] = __builtin_amdgcn_mfma_f32_16x16x32_bf16(a[i], b[j], acc[i][j], 0, 0, 0);
    }
  }

  if (outBf16){
    u16* C = (u16*)Cp;
#pragma unroll
    for (int i = 0; i < 4; i++)
#pragma unroll
      for (int r = 0; r < 4; r++){
        int gm = bm + wr + i*16 + lgrp*4 + r;
        u16* crow = C + (size_t)gm * N + bn + wc + lrow;
#pragma unroll
        for (int j = 0; j < 4; j++) crow[j*16] = f2b(acc[i][j][r]);
      }
  } else {
    float* C = (float*)Cp;
#pragma unroll
    for (int i = 0; i < 4; i++)
#pragma unroll
      for (int r = 0; r < 4; r++){
        int gm = bm + wr + i*16 + lgrp*4 + r;
        float* crow = C + (size_t)gm * N + bn + wc + lrow;
#pragma unroll
        for (int j = 0; j < 4; j++) crow[j*16] = acc[i][j][r];
      }
  }
}

// ---------- LoRA rank-16 add ----------
__global__ void k_lora_add_b(u16* __restrict__ y, const float* __restrict__ t,
                             const float* __restrict__ l2, int roff){
  int o = blockIdx.x * 256 + threadIdx.x;
  int m = blockIdx.y;
  const fx4* tv = (const fx4*)(t + (size_t)m * 128 + roff);
  const fx4* lv = (const fx4*)(l2 + (size_t)o * 16);
  float s = 0.f;
#pragma unroll
  for (int r = 0; r < 4; r++){
    fx4 a = tv[r], b = lv[r];
    s += a[0]*b[0] + a[1]*b[1] + a[2]*b[2] + a[3]*b[3];
  }
  size_t idx = (size_t)m * DIMz + o;
  y[idx] = f2b(b2f(y[idx]) + s);
}

__global__ void k_lora_add_f(float* __restrict__ y, const float* __restrict__ t,
                             const float* __restrict__ l2, int roff){
  int o = blockIdx.x * 256 + threadIdx.x;
  int m = blockIdx.y;
  const fx4* tv = (const fx4*)(t + (size_t)m * 128 + roff);
  const fx4* lv = (const fx4*)(l2 + (size_t)o * 16);
  float s = 0.f;
#pragma unroll
  for (int r = 0; r < 4; r++){
    fx4 a = tv[r], b = lv[r];
    s += a[0]*b[0] + a[1]*b[1] + a[2]*b[2] + a[3]*b[3];
  }
  y[(size_t)m * DIMz + o] += s;
}

// ---------- RoPE + (B,S,DIM)->(B,H,S,HD) ----------
__global__ void k_rope(const u16* __restrict__ x, u16* __restrict__ out,
                       const float* __restrict__ fcos, const float* __restrict__ fsin){
  int m = blockIdx.x;
  int b = m >> 10, s = m & 1023;
#pragma unroll
  for (int i = 0; i < 8; i++){
    int p = i * 256 + threadIdx.x;
    int h = p >> 6, j = p & 63;
    size_t xi = (size_t)m * DIMz + h * HDz + 2 * j;
    float r = b2f(x[xi]), im = b2f(x[xi + 1]);
    float c = fcos[s * 64 + j], sn = fsin[s * 64 + j];
    size_t oi = (((size_t)b * Hz + h) * Sz + s) * HDz + 2 * j;
    out[oi]     = f2b(r * c - im * sn);
    out[oi + 1] = f2b(r * sn + im * c);
  }
}

// ---------- V: (B,S,H,HD) -> Vt (B,H,HD,S) ----------
__global__ void k_vtrans(const u16* __restrict__ x, u16* __restrict__ vt){
  __shared__ __align__(16) u16 tile[64][128];
  int bh = blockIdx.y;
  int b = bh >> 5, h = bh & 31;
  int s0 = blockIdx.x * 64;
  int tid = threadIdx.x;
#pragma unroll
  for (int i = 0; i < 4; i++){
    int c = i * 256 + tid;
    int ss = c >> 4, d8 = (c & 15) << 3;
    *(short8*)&tile[ss][d8] =
      *(const short8*)&x[(size_t)(b * Sz + s0 + ss) * DIMz + h * HDz + d8];
  }
  __syncthreads();
#pragma unroll
  for (int i = 0; i < 4; i++){
    int c = i * 256 + tid;
    int d = c >> 3, s8 = (c & 7) << 3;
    short8 v;
#pragma unroll
    for (int k = 0; k < 8; k++) v[k] = (short)tile[s8 + k][d];
    *(short8*)&vt[((size_t)bh * HDz + d) * Sz + s0 + s8] = v;
  }
}

// ---------- adapter K/V reshape ----------
__global__ void k_adresh(const u16* __restrict__ akf, const u16* __restrict__ avf,
                         u16* __restrict__ AK, u16* __restrict__ AVt){
  int bh = blockIdx.x;
  int b = bh >> 5, h = bh & 31;
  int tid = threadIdx.x;
#pragma unroll
  for (int i = 0; i < 8; i++){
    int e = i * 256 + tid;
    int jj = e >> 7, d = e & 127;
    u16 v = (jj < ALz) ? akf[(size_t)(b * ALz + jj) * DIMz + h * HDz + d] : (u16)0;
    AK[((size_t)bh * 16 + jj) * HDz + d] = v;
  }
#pragma unroll
  for (int i = 0; i < 16; i++){
    int e = i * 256 + tid;
    int d = e >> 5, jj = e & 31;
    u16 v = (jj < ALz) ? avf[(size_t)(b * ALz + jj) * DIMz + h * HDz + d] : (u16)0;
    AVt[((size_t)bh * HDz + d) * 32 + jj] = v;
  }
}

// ---------- flash attention + gated adapter attention ----------
// v2: QBLK=128, 8 waves, double-buffered async K/V staging, defer-max, wave causal skip.
// LDS: Ks 32K + Vs 32K + Ps 16K = 80KB -> 2 blocks/CU (16 waves).
__global__ __launch_bounds__(512)
void k_attn(const u16* __restrict__ Q, const u16* __restrict__ Kg,
            const u16* __restrict__ Vt, const u16* __restrict__ AKg,
            const u16* __restrict__ AVg, const float* __restrict__ gate,
            u16* __restrict__ outp){
  __shared__ __align__(16) u16 Ks[2][64][128];
  __shared__ __align__(16) u16 Vs[2][128][64];
  __shared__ __align__(16) u16 Ps[8][16][64];

  const int bh = blockIdx.y;
  const int b = bh >> 5, h = bh & 31;
  const int q0 = blockIdx.x * 128;
  const int tid = threadIdx.x;
  const int w = tid >> 6, l = tid & 63;
  const int lrow = l & 15, lgrp = l >> 4;

  const u16* Qb = Q  + (size_t)bh * (Sz * HDz) + (size_t)q0 * HDz;
  const u16* Kb = Kg + (size_t)bh * (Sz * HDz);
  const u16* Vb = Vt + (size_t)bh * (HDz * Sz);
  u16* PsB = &Ps[0][0][0];

  short8 aq[4];
#pragma unroll
  for (int kk = 0; kk < 4; kk++)
    aq[kk] = *(const short8*)&Qb[(size_t)(w*16 + lrow) * HDz + kk*32 + lgrp*8];

  const fx4 fz = {0.f, 0.f, 0.f, 0.f};
  fx4 o[8];
#pragma unroll
  for (int i = 0; i < 8; i++) o[i] = fz;
  float mrow[4], lsum[4];
#pragma unroll
  for (int r = 0; r < 4; r++){ mrow[r] = -1e30f; lsum[r] = 0.f; }

  const float scale = 0.088388347648318447f; // 1/sqrt(128)
  const int qwbase = q0 + w * 16;
  const int qrowbase = qwbase + lgrp * 4;
  const int ktiles = 2 * blockIdx.x + 2;

  auto STAGE = [&](int buf, int kt){
    const int k0 = kt * 64;
#pragma unroll
    for (int r = 0; r < 2; r++){
      int c = r * 512 + tid;                // 1024 chunks: K 64x128 u16
      int row = c >> 4, cs = c & 15;
      int gcs = cs ^ (row & 7);
      gload16(Kb + (size_t)(k0 + row) * HDz + gcs * 8, ((u16*)&Ks[buf][0][0]) + c * 8);
    }
#pragma unroll
    for (int r = 0; r < 2; r++){
      int c = r * 512 + tid;                // 1024 chunks: V 128x64 u16
      int row = c >> 3, cs = c & 7;
      int gcs = cs ^ (row & 7);
      gload16(Vb + (size_t)row * Sz + k0 + gcs * 8, ((u16*)&Vs[buf][0][0]) + c * 8);
    }
  };

  STAGE(0, 0);
  asm volatile("s_waitcnt vmcnt(0)" ::: "memory");
  bar();

  for (int kt = 0; kt < ktiles; kt++){
    const int cur = kt & 1;
    if (kt + 1 < ktiles) STAGE(cur ^ 1, kt + 1);   // async: lands during compute
    const int k0 = kt * 64;

    if (k0 <= qwbase + 15){   // wave-level causal skip (tile fully above diagonal)
      fx4 sc[4];
#pragma unroll
      for (int j = 0; j < 4; j++) sc[j] = fz;
#pragma unroll
      for (int kk = 0; kk < 4; kk++){
#pragma unroll
        for (int j = 0; j < 4; j++){
          short8 bk = *ldsRd(&Ks[cur][0][0], 256, j*16 + lrow, kk*32 + lgrp*8);
          sc[j] = __builtin_amdgcn_mfma_f32_16x16x32_bf16(aq[kk], bk, sc[j], 0, 0, 0);
        }
      }
      const bool domask = (k0 + 63 > qwbase);
      float tm[4];
#pragma unroll
      for (int r = 0; r < 4; r++){
        float mx = -1e30f;
#pragma unroll
        for (int j = 0; j < 4; j++){
          float v = sc[j][r] * scale;
          if (domask){
            int kcol = k0 + j*16 + lrow;
            if (kcol > qrowbase + r) v = -1e30f;
          }
          sc[j][r] = v;
          mx = fmaxf(mx, v);
        }
#pragma unroll
        for (int d = 1; d < 16; d <<= 1) mx = fmaxf(mx, __shfl_xor(mx, d));
        tm[r] = mx;
      }
      // defer-max (T13, THR=8): skip o-rescale when tile max stays bounded
      if (!__all(tm[0] <= mrow[0] + 8.f && tm[1] <= mrow[1] + 8.f &&
                 tm[2] <= mrow[2] + 8.f && tm[3] <= mrow[3] + 8.f)){
        float esc[4];
#pragma unroll
        for (int r = 0; r < 4; r++){
          float nm = fmaxf(mrow[r], tm[r]);
          esc[r] = __expf(mrow[r] - nm);
          mrow[r] = nm;
          lsum[r] *= esc[r];
        }
#pragma unroll
        for (int j = 0; j < 8; j++)
#pragma unroll
          for (int r = 0; r < 4; r++) o[j][r] *= esc[r];
      }
#pragma unroll
      for (int r = 0; r < 4; r++){
        float s = 0.f;
#pragma unroll
        for (int j = 0; j < 4; j++){
          float p = __expf(sc[j][r] - mrow[r]);
          sc[j][r] = p;
          s += p;
        }
#pragma unroll
        for (int d = 1; d < 16; d <<= 1) s += __shfl_xor(s, d);
        lsum[r] += s;
      }
#pragma unroll
      for (int j = 0; j < 4; j++)
#pragma unroll
        for (int r = 0; r < 4; r++)
          *psPtr(PsB, w, lgrp*4 + r, j*16 + lrow) = f2b(sc[j][r]);
#pragma unroll
      for (int kk = 0; kk < 2; kk++){
        short8 ap = *(const short8*)psPtr(PsB, w, lrow, kk*32 + lgrp*8);
#pragma unroll
        for (int j = 0; j < 8; j++){
          short8 bv = *ldsRd(&Vs[cur][0][0], 128, j*16 + lrow, kk*32 + lgrp*8);
          o[j] = __builtin_amdgcn_mfma_f32_16x16x32_bf16(ap, bv, o[j], 0, 0, 0);
        }
      }
    }

    asm volatile("s_waitcnt vmcnt(0)" ::: "memory");  // next tile's loads landed
    bar();
  }

#pragma unroll
  for (int j = 0; j < 8; j++)
#pragma unroll
    for (int r = 0; r < 4; r++) o[j][r] /= lsum[r];

  // adapter attention (K/V direct from global; once per block)
  fx4 s2 = fz;
  const u16* AKb = AKg + (size_t)bh * (16 * HDz);
#pragma unroll
  for (int kk = 0; kk < 4; kk++){
    short8 bk = *(const short8*)&AKb[(size_t)lrow * HDz + kk*32 + lgrp*8];
    s2 = __builtin_amdgcn_mfma_f32_16x16x32_bf16(aq[kk], bk, s2, 0, 0, 0);
  }
  const float g = tanhf(gate[h]);
#pragma unroll
  for (int r = 0; r < 4; r++){
    float v = s2[r] * scale;
    if (lrow >= ALz) v = -1e30f;
    float mx = v;
#pragma unroll
    for (int d = 1; d < 16; d <<= 1) mx = fmaxf(mx, __shfl_xor(mx, d));
    float p = __expf(v - mx);
    float s = p;
#pragma unroll
    for (int d = 1; d < 16; d <<= 1) s += __shfl_xor(s, d);
    float p2 = g * p / s;
    *psPtr(PsB, w, lgrp*4 + r, lrow) = f2b(p2);
    *psPtr(PsB, w, lgrp*4 + r, 16 + lrow) = 0;
  }
  {
    const u16* AVb = AVg + (size_t)bh * (HDz * 32);
    short8 ap = *(const short8*)psPtr(PsB, w, lrow, lgrp*8);
#pragma unroll
    for (int j = 0; j < 8; j++){
      short8 bv = *(const short8*)&AVb[(size_t)(j*16 + lrow) * 32 + lgrp*8];
      o[j] = __builtin_amdgcn_mfma_f32_16x16x32_bf16(ap, bv, o[j], 0, 0, 0);
    }
  }

  u16* ob = outp + (size_t)(b * Sz + q0) * DIMz + h * HDz;
#pragma unroll
  for (int j = 0; j < 8; j++)
#pragma unroll
    for (int r = 0; r < 4; r++){
      int row = w*16 + lgrp*4 + r;
      ob[(size_t)row * DIMz + j*16 + lrow] = f2b(o[j][r]);
    }
}

// ---------- host ----------
extern "C" void kernel_launch(void* const* d_in, const int* in_sizes, int n_in,
                              void* d_out, int out_size, void* d_ws, size_t ws_size,
                              hipStream_t stream){
  const float* x    = (const float*)d_in[0];
  const float* adap = (const float*)d_in[1];
  const float* wq   = (const float*)d_in[2];
  const float* wk   = (const float*)d_in[3];
  const float* wv   = (const float*)d_in[4];
  const float* wo   = (const float*)d_in[5];
  const float* lq1  = (const float*)d_in[6];
  const float* lq2  = (const float*)d_in[7];
  const float* lk1  = (const float*)d_in[8];
  const float* lk2  = (const float*)d_in[9];
  const float* lv1  = (const float*)d_in[10];
  const float* lv2  = (const float*)d_in[11];
  const float* lo1  = (const float*)d_in[12];
  const float* lo2  = (const float*)d_in[13];
  const float* gate = (const float*)d_in[14];
  const float* fcos = (const float*)d_in[15];
  const float* fsin = (const float*)d_in[16];

  const size_t MB = 1024 * 1024;
  char* ws = (char*)d_ws;
  u16*  Xcat = (u16*)(ws);                 // 4352x4096 bf16 (34 MB); later Q
  u16*  Wb   = (u16*)(ws + 34 * MB);       // 32 MB; later K
  u16*  xq   = (u16*)(ws + 66 * MB);       // 34 MB; later attn_out
  u16*  xk   = (u16*)(ws + 100 * MB);      // 34 MB
  u16*  xv   = (u16*)(ws + 134 * MB);      // 34 MB
  u16*  Vt   = (u16*)(ws + 168 * MB);      // 32 MB; t (f32) aliases (disjoint lifetimes)
  float* t   = (float*)(ws + 168 * MB);
  u16*  l1b  = (u16*)(ws + 200 * MB);      // 1 MB
  u16*  AKb  = (u16*)(ws + 201 * MB);      // 0.5 MB
  u16*  AVb  = (u16*)(ws + 201 * MB + 512 * 1024); // 1 MB
  u16*  Qb = Xcat;
  u16*  Kb = Wb;
  u16*  attn = xq;
  float* out = (float*)d_out;

  dim3 blk(256);
  const int MCAT = 4352;
  const u16* Xad = Xcat + (size_t)4096 * 4096;

  k_xcat<<<dim3(MCAT * 4096 / 1024), blk, 0, stream>>>(x, adap, Xcat);

  k_f2b_pad<<<dim3(4096 * 4096 / 1024), blk, 0, stream>>>(wq, Wb, 4096, 4096, 4096);
  gemm_nt256<<<dim3(256), dim3(512), 0, stream>>>(Xcat, Wb, xq, 4096, 4096, 1, 16);
  k_f2b_pad<<<dim3(4096 * 4096 / 1024), blk, 0, stream>>>(wk, Wb, 4096, 4096, 4096);
  gemm_nt256<<<dim3(256), dim3(512), 0, stream>>>(Xcat, Wb, xk, 4096, 4096, 1, 16);
  k_adgemm<<<dim3(64), blk, 0, stream>>>(Xad, Wb, xk + (size_t)4096 * 4096, 4096, 4096);
  k_f2b_pad<<<dim3(4096 * 4096 / 1024), blk, 0, stream>>>(wv, Wb, 4096, 4096, 4096);
  gemm_nt256<<<dim3(256), dim3(512), 0, stream>>>(Xcat, Wb, xv, 4096, 4096, 1, 16);
  k_adgemm<<<dim3(64), blk, 0, stream>>>(Xad, Wb, xv + (size_t)4096 * 4096, 4096, 4096);

  k_l1cat<<<dim3(128 * 4096 / 1024), blk, 0, stream>>>(lq1, lk1, lv1, l1b);
  gemm_nt<<<dim3(1, 32), blk, 0, stream>>>(Xcat, l1b, t, 4096, 128, 4096, 0);
  k_lora_add_b<<<dim3(16, 4096), blk, 0, stream>>>(xq, t, lq2, 0);
  k_lora_add_b<<<dim3(16, 4096), blk, 0, stream>>>(xk, t, lk2, 16);
  k_lora_add_b<<<dim3(16, 4096), blk, 0, stream>>>(xv, t, lv2, 32);

  k_rope<<<dim3(4096), blk, 0, stream>>>(xq, Qb, fcos, fsin);
  k_rope<<<dim3(4096), blk, 0, stream>>>(xk, Kb, fcos, fsin);
  k_vtrans<<<dim3(16, 128), blk, 0, stream>>>(xv, Vt);
  k_adresh<<<dim3(128), blk, 0, stream>>>(xk + (size_t)4096 * 4096,
                                          xv + (size_t)4096 * 4096, AKb, AVb);

  k_attn<<<dim3(8, 128), dim3(512), 0, stream>>>(Qb, Kb, Vt, AKb, AVb, gate, attn);

  k_f2b_pad<<<dim3(4096 * 4096 / 1024), blk, 0, stream>>>(wo, Wb, 4096, 4096, 4096);
  gemm_nt256<<<dim3(256), dim3(512), 0, stream>>>(attn, Wb, out, 4096, 4096, 0, 16);
  k_f2b_pad<<<dim3(128 * 4096 / 1024), blk, 0, stream>>>(lo1, l1b, 16, 4096, 128);
  gemm_nt<<<dim3(1, 32), blk, 0, stream>>>(attn, l1b, t, 4096, 128, 4096, 0);
  k_lora_add_f<<<dim3(16, 4096), blk, 0, stream>>>(out, t, lo2, 0);
}

// Round 9
// 1243.220 us; speedup vs baseline: 1.2476x; 1.0439x over previous
//
#include <hip/hip_runtime.h>
#include <stdint.h>

#define Bz 4
#define Sz 1024
#define DIMz 4096
#define Hz 32
#define HDz 128
#define ALz 10

typedef unsigned short u16;
typedef __attribute__((ext_vector_type(8))) short short8;
typedef __attribute__((ext_vector_type(4))) float fx4;

__device__ __forceinline__ u16 f2b(float f){
  union { float f; unsigned u; } v; v.f = f;
  unsigned r = v.u + 0x7FFFu + ((v.u >> 16) & 1u);
  return (u16)(r >> 16);
}
__device__ __forceinline__ float b2f(u16 h){
  union { unsigned u; float f; } v; v.u = ((unsigned)h) << 16; return v.f;
}
__device__ __forceinline__ void gload16(const void* g, void* l){
  __builtin_amdgcn_global_load_lds(
    (const __attribute__((address_space(1))) uint32_t*)g,
    (__attribute__((address_space(3))) uint32_t*)l, 16, 0, 0);
}
__device__ __forceinline__ void bar(){
  asm volatile("" ::: "memory");
  __builtin_amdgcn_s_barrier();
  asm volatile("" ::: "memory");
}

// ---------- LDS swizzle helper (T2: byte ^= (row&7)<<4) ----------
__device__ __forceinline__ const short8* ldsRd(const u16* base, int rowBytes, int row, int colElem){
  unsigned byte = (unsigned)(row * rowBytes + colElem * 2);
  byte ^= (unsigned)((row & 7) << 4);
  return (const short8*)((const char*)base + byte);
}
__device__ __forceinline__ u16* psPtr(u16* base, int w, int row, int colElem){
  unsigned byte = (unsigned)(row * 128 + colElem * 2);
  byte ^= (unsigned)((row & 7) << 4);
  return (u16*)((char*)base + w * 2048 + byte);
}

// ---------- conversions ----------
__global__ void k_f2b_pad(const float* __restrict__ src, u16* __restrict__ dst,
                          int srcRows, int cols, int dstRows){
  size_t i = (size_t)blockIdx.x * 1024 + (size_t)threadIdx.x * 4;
  int row = (int)(i / cols);
  if (row < srcRows){
    fx4 v = *(const fx4*)(src + i);
    dst[i] = f2b(v[0]); dst[i+1] = f2b(v[1]); dst[i+2] = f2b(v[2]); dst[i+3] = f2b(v[3]);
  } else {
    dst[i] = 0; dst[i+1] = 0; dst[i+2] = 0; dst[i+3] = 0;
  }
}

__global__ void k_xcat(const float* __restrict__ x, const float* __restrict__ ad,
                       u16* __restrict__ dst){
  size_t i = (size_t)blockIdx.x * 1024 + (size_t)threadIdx.x * 4;
  int row = (int)(i >> 12);
  int col = (int)(i & 4095);
  const float* s = nullptr;
  if (row < 4096) s = x + i;
  else if (row < 4096 + Bz*ALz) s = ad + (size_t)(row - 4096) * DIMz + col;
  if (s){
    fx4 v = *(const fx4*)s;
    dst[i] = f2b(v[0]); dst[i+1] = f2b(v[1]); dst[i+2] = f2b(v[2]); dst[i+3] = f2b(v[3]);
  } else {
    dst[i] = 0; dst[i+1] = 0; dst[i+2] = 0; dst[i+3] = 0;
  }
}

__global__ void k_l1cat(const float* __restrict__ a, const float* __restrict__ b,
                        const float* __restrict__ c, u16* __restrict__ dst){
  size_t i = (size_t)blockIdx.x * 1024 + (size_t)threadIdx.x * 4;
  int row = (int)(i >> 12);
  int col = (int)(i & 4095);
  const float* s = nullptr;
  if (row < 16) s = a + (size_t)row * 4096 + col;
  else if (row < 32) s = b + (size_t)(row - 16) * 4096 + col;
  else if (row < 48) s = c + (size_t)(row - 32) * 4096 + col;
  if (s){
    fx4 v = *(const fx4*)s;
    dst[i] = f2b(v[0]); dst[i+1] = f2b(v[1]); dst[i+2] = f2b(v[2]); dst[i+3] = f2b(v[3]);
  } else {
    dst[i] = 0; dst[i+1] = 0; dst[i+2] = 0; dst[i+3] = 0;
  }
}

// ---------- 256x256 8-phase counted-vmcnt NT bf16 GEMM ----------
#define PHASE(BUF, P, STAGE_STMT, VM_STMT)                                          \
  {                                                                                 \
    if ((P) == 0){                                                                  \
      _Pragma("unroll")                                                             \
      for (int nj = 0; nj < 4; nj++)                                                \
        _Pragma("unroll")                                                           \
        for (int kk = 0; kk < 2; kk++)                                              \
          bf[nj][kk] = *ldsRd(&lds[BUF][2 + (wn >> 1)][0][0], 128,                  \
                              (wn & 1) * 64 + nj * 16 + lrow, kk * 32 + lgrp * 8);  \
    }                                                                               \
    short8 af[2][2];                                                                \
    _Pragma("unroll")                                                               \
    for (int m2 = 0; m2 < 2; m2++)                                                  \
      _Pragma("unroll")                                                             \
      for (int kk = 0; kk < 2; kk++)                                                \
        af[m2][kk] = *ldsRd(&lds[BUF][wm][0][0], 128,                               \
                            ((P) * 2 + m2) * 16 + lrow, kk * 32 + lgrp * 8);        \
    STAGE_STMT;                                                                     \
    bar();                                                                          \
    __builtin_amdgcn_s_setprio(1);                                                  \
    _Pragma("unroll")                                                               \
    for (int m2 = 0; m2 < 2; m2++)                                                  \
      _Pragma("unroll")                                                             \
      for (int nj = 0; nj < 4; nj++)                                                \
        _Pragma("unroll")                                                           \
        for (int kk = 0; kk < 2; kk++)                                              \
          acc[(P) * 2 + m2][nj] = __builtin_amdgcn_mfma_f32_16x16x32_bf16(          \
              af[m2][kk], bf[nj][kk], acc[(P) * 2 + m2][nj], 0, 0, 0);              \
    __builtin_amdgcn_s_setprio(0);                                                  \
    VM_STMT;                                                                        \
    bar();                                                                          \
  }

__global__ __launch_bounds__(512, 2)
void gemm_nt256(const u16* __restrict__ A, const u16* __restrict__ Bm,
                void* __restrict__ Cp, int N, int K, int outBf16, int nbx){
  __shared__ __align__(16) u16 lds[2][4][128][64];
  const int tid = threadIdx.x;
  const int l = tid & 63, w = tid >> 6;
  const int lrow = l & 15, lgrp = l >> 4;
  const int wm = w >> 2, wn = w & 3;

  const int nwg = gridDim.x;
  const int cpx = nwg >> 3;
  const int swz = (blockIdx.x & 7) * cpx + (blockIdx.x >> 3);
  const int by = swz / nbx, bx = swz - by * nbx;
  const int bm = by << 8, bn = bx << 8;

  const u16* A0s = A  + (size_t)bm * K;
  const u16* A1s = A0s + (size_t)128 * K;
  const u16* B0s = Bm + (size_t)bn * K;
  const u16* B1s = B0s + (size_t)128 * K;
  const int nt = K >> 6;

  const fx4 fz = {0.f, 0.f, 0.f, 0.f};
  fx4 acc[8][4];
#pragma unroll
  for (int i = 0; i < 8; i++)
#pragma unroll
    for (int j = 0; j < 4; j++) acc[i][j] = fz;

  auto STAGEH = [&](int buf, int reg, const u16* src, int t){
#pragma unroll
    for (int r = 0; r < 2; r++){
      int c = r * 512 + tid;
      int row = c >> 3, cs = c & 7;
      int off = (cs ^ (row & 7)) << 3;
      gload16(src + (size_t)row * K + t * 64 + off, &lds[buf][reg][0][0] + c * 8);
    }
  };

  STAGEH(0, 0, A0s, 0); STAGEH(0, 1, A1s, 0);
  STAGEH(0, 2, B0s, 0); STAGEH(0, 3, B1s, 0);
  STAGEH(1, 2, B0s, 1); STAGEH(1, 3, B1s, 1);
  asm volatile("s_waitcnt vmcnt(4)" ::: "memory");
  bar();

  short8 bf[4][2];
  const int ni = nt >> 1;
  for (int i = 0; i < ni; i++){
    const int t0 = 2 * i, t1 = 2 * i + 1;
    const bool more = (i < ni - 1);
    PHASE(0, 0, { STAGEH(1, 0, A0s, t1); }, {});
    PHASE(0, 1, { STAGEH(1, 1, A1s, t1); }, {});
    PHASE(0, 2, { if (more) STAGEH(0, 2, B0s, t0 + 2); }, {});
    PHASE(0, 3, { if (more) STAGEH(0, 3, B1s, t0 + 2); },
          { if (more) { asm volatile("s_waitcnt vmcnt(4)" ::: "memory"); }
            else      { asm volatile("s_waitcnt vmcnt(0)" ::: "memory"); } });
    PHASE(1, 0, { if (more) STAGEH(0, 0, A0s, t0 + 2); }, {});
    PHASE(1, 1, { if (more) STAGEH(0, 1, A1s, t0 + 2); }, {});
    PHASE(1, 2, { if (more) STAGEH(1, 2, B0s, t1 + 2); }, {});
    PHASE(1, 3, { if (more) STAGEH(1, 3, B1s, t1 + 2); },
          { if (more) { asm volatile("s_waitcnt vmcnt(4)" ::: "memory"); } });
  }

  if (outBf16){
    u16* C = (u16*)Cp;
#pragma unroll
    for (int mi = 0; mi < 8; mi++)
#pragma unroll
      for (int r = 0; r < 4; r++){
        int gm = bm + wm * 128 + mi * 16 + lgrp * 4 + r;
        u16* crow = C + (size_t)gm * N + bn + wn * 64 + lrow;
#pragma unroll
        for (int nj = 0; nj < 4; nj++) crow[nj * 16] = f2b(acc[mi][nj][r]);
      }
  } else {
    float* C = (float*)Cp;
#pragma unroll
    for (int mi = 0; mi < 8; mi++)
#pragma unroll
      for (int r = 0; r < 4; r++){
        int gm = bm + wm * 128 + mi * 16 + lgrp * 4 + r;
        float* crow = C + (size_t)gm * N + bn + wn * 64 + lrow;
#pragma unroll
        for (int nj = 0; nj < 4; nj++) crow[nj * 16] = acc[mi][nj][r];
      }
  }
}

// ---------- thin adapter GEMM ----------
__global__ __launch_bounds__(256)
void k_adgemm(const u16* __restrict__ A, const u16* __restrict__ Bm,
              u16* __restrict__ C, int N, int K){
  const int tid = threadIdx.x;
  const int w = tid >> 6, l = tid & 63;
  const int lrow = l & 15, lgrp = l >> 4;
  const int n0 = blockIdx.x * 64 + w * 16;

  const fx4 fz = {0.f, 0.f, 0.f, 0.f};
  fx4 acc[3];
#pragma unroll
  for (int i = 0; i < 3; i++) acc[i] = fz;

  const u16* Brow = Bm + (size_t)(n0 + lrow) * K + lgrp * 8;
  const u16* Arow = A + (size_t)lrow * K + lgrp * 8;
#pragma unroll 2
  for (int k0 = 0; k0 < K; k0 += 32){
    short8 b = *(const short8*)(Brow + k0);
#pragma unroll
    for (int mf = 0; mf < 3; mf++){
      short8 a = *(const short8*)(Arow + (size_t)mf * 16 * K + k0);
      acc[mf] = __builtin_amdgcn_mfma_f32_16x16x32_bf16(a, b, acc[mf], 0, 0, 0);
    }
  }
#pragma unroll
  for (int mf = 0; mf < 3; mf++)
#pragma unroll
    for (int r = 0; r < 4; r++)
      C[(size_t)(mf * 16 + lgrp * 4 + r) * N + n0 + lrow] = f2b(acc[mf][r]);
}

// ---------- 128x128 NT bf16 GEMM (small-N LoRA gemms) ----------
__global__ __launch_bounds__(256)
void gemm_nt(const u16* __restrict__ A, const u16* __restrict__ Bm, void* __restrict__ Cp,
             int M, int N, int K, int outBf16){
  __shared__ __align__(16) u16 As[128][64];
  __shared__ __align__(16) u16 Bs[128][64];
  const int tid = threadIdx.x;
  const int w = tid >> 6, l = tid & 63;
  const int lrow = l & 15, lgrp = l >> 4;
  const int bm = blockIdx.y * 128, bn = blockIdx.x * 128;
  const int wr = (w >> 1) * 64, wc = (w & 1) * 64;

  const fx4 fz = {0.f, 0.f, 0.f, 0.f};
  fx4 acc[4][4];
#pragma unroll
  for (int i = 0; i < 4; i++)
#pragma unroll
    for (int j = 0; j < 4; j++) acc[i][j] = fz;

  const u16* Abase = A + (size_t)bm * K;
  const u16* Bbase = Bm + (size_t)bn * K;

  for (int k0 = 0; k0 < K; k0 += 64){
    __syncthreads();
#pragma unroll
    for (int i = 0; i < 4; i++){
      int c = i * 256 + tid;
      int row = c >> 3, cs = c & 7;
      int off = (cs ^ (row & 7)) << 3;
      gload16(Abase + (size_t)row * K + k0 + off, ((u16*)As) + c * 8);
      gload16(Bbase + (size_t)row * K + k0 + off, ((u16*)Bs) + c * 8);
    }
    __syncthreads();
#pragma unroll
    for (int kk = 0; kk < 2; kk++){
      short8 a[4], b[4];
#pragma unroll
      for (int i = 0; i < 4; i++) a[i] = *ldsRd(&As[0][0], 128, wr + i*16 + lrow, kk*32 + lgrp*8);
#pragma unroll
      for (int j = 0; j < 4; j++) b[j] = *ldsRd(&Bs[0][0], 128, wc + j*16 + lrow, kk*32 + lgrp*8);
#pragma unroll
      for (int i = 0; i < 4; i++)
#pragma unroll
        for (int j = 0; j < 4; j++)
          acc[i][j] = __builtin_amdgcn_mfma_f32_16x16x32_bf16(a[i], b[j], acc[i][j], 0, 0, 0);
    }
  }

  if (outBf16){
    u16* C = (u16*)Cp;
#pragma unroll
    for (int i = 0; i < 4; i++)
#pragma unroll
      for (int r = 0; r < 4; r++){
        int gm = bm + wr + i*16 + lgrp*4 + r;
        u16* crow = C + (size_t)gm * N + bn + wc + lrow;
#pragma unroll
        for (int j = 0; j < 4; j++) crow[j*16] = f2b(acc[i][j][r]);
      }
  } else {
    float* C = (float*)Cp;
#pragma unroll
    for (int i = 0; i < 4; i++)
#pragma unroll
      for (int r = 0; r < 4; r++){
        int gm = bm + wr + i*16 + lgrp*4 + r;
        float* crow = C + (size_t)gm * N + bn + wc + lrow;
#pragma unroll
        for (int j = 0; j < 4; j++) crow[j*16] = acc[i][j][r];
      }
  }
}

// ---------- LoRA rank-16 add ----------
__global__ void k_lora_add_b(u16* __restrict__ y, const float* __restrict__ t,
                             const float* __restrict__ l2, int roff){
  int o = blockIdx.x * 256 + threadIdx.x;
  int m = blockIdx.y;
  const fx4* tv = (const fx4*)(t + (size_t)m * 128 + roff);
  const fx4* lv = (const fx4*)(l2 + (size_t)o * 16);
  float s = 0.f;
#pragma unroll
  for (int r = 0; r < 4; r++){
    fx4 a = tv[r], b = lv[r];
    s += a[0]*b[0] + a[1]*b[1] + a[2]*b[2] + a[3]*b[3];
  }
  size_t idx = (size_t)m * DIMz + o;
  y[idx] = f2b(b2f(y[idx]) + s);
}

__global__ void k_lora_add_f(float* __restrict__ y, const float* __restrict__ t,
                             const float* __restrict__ l2, int roff){
  int o = blockIdx.x * 256 + threadIdx.x;
  int m = blockIdx.y;
  const fx4* tv = (const fx4*)(t + (size_t)m * 128 + roff);
  const fx4* lv = (const fx4*)(l2 + (size_t)o * 16);
  float s = 0.f;
#pragma unroll
  for (int r = 0; r < 4; r++){
    fx4 a = tv[r], b = lv[r];
    s += a[0]*b[0] + a[1]*b[1] + a[2]*b[2] + a[3]*b[3];
  }
  y[(size_t)m * DIMz + o] += s;
}

// ---------- RoPE + (B,S,DIM)->(B,H,S,HD) ----------
__global__ void k_rope(const u16* __restrict__ x, u16* __restrict__ out,
                       const float* __restrict__ fcos, const float* __restrict__ fsin){
  int m = blockIdx.x;
  int b = m >> 10, s = m & 1023;
#pragma unroll
  for (int i = 0; i < 8; i++){
    int p = i * 256 + threadIdx.x;
    int h = p >> 6, j = p & 63;
    size_t xi = (size_t)m * DIMz + h * HDz + 2 * j;
    float r = b2f(x[xi]), im = b2f(x[xi + 1]);
    float c = fcos[s * 64 + j], sn = fsin[s * 64 + j];
    size_t oi = (((size_t)b * Hz + h) * Sz + s) * HDz + 2 * j;
    out[oi]     = f2b(r * c - im * sn);
    out[oi + 1] = f2b(r * sn + im * c);
  }
}

// ---------- V: (B,S,H,HD) -> Vt (B,H,HD,S) ----------
__global__ void k_vtrans(const u16* __restrict__ x, u16* __restrict__ vt){
  __shared__ __align__(16) u16 tile[64][128];
  int bh = blockIdx.y;
  int b = bh >> 5, h = bh & 31;
  int s0 = blockIdx.x * 64;
  int tid = threadIdx.x;
#pragma unroll
  for (int i = 0; i < 4; i++){
    int c = i * 256 + tid;
    int ss = c >> 4, d8 = (c & 15) << 3;
    *(short8*)&tile[ss][d8] =
      *(const short8*)&x[(size_t)(b * Sz + s0 + ss) * DIMz + h * HDz + d8];
  }
  __syncthreads();
#pragma unroll
  for (int i = 0; i < 4; i++){
    int c = i * 256 + tid;
    int d = c >> 3, s8 = (c & 7) << 3;
    short8 v;
#pragma unroll
    for (int k = 0; k < 8; k++) v[k] = (short)tile[s8 + k][d];
    *(short8*)&vt[((size_t)bh * HDz + d) * Sz + s0 + s8] = v;
  }
}

// ---------- adapter K/V reshape ----------
__global__ void k_adresh(const u16* __restrict__ akf, const u16* __restrict__ avf,
                         u16* __restrict__ AK, u16* __restrict__ AVt){
  int bh = blockIdx.x;
  int b = bh >> 5, h = bh & 31;
  int tid = threadIdx.x;
#pragma unroll
  for (int i = 0; i < 8; i++){
    int e = i * 256 + tid;
    int jj = e >> 7, d = e & 127;
    u16 v = (jj < ALz) ? akf[(size_t)(b * ALz + jj) * DIMz + h * HDz + d] : (u16)0;
    AK[((size_t)bh * 16 + jj) * HDz + d] = v;
  }
#pragma unroll
  for (int i = 0; i < 16; i++){
    int e = i * 256 + tid;
    int d = e >> 5, jj = e & 31;
    u16 v = (jj < ALz) ? avf[(size_t)(b * ALz + jj) * DIMz + h * HDz + d] : (u16)0;
    AVt[((size_t)bh * HDz + d) * 32 + jj] = v;
  }
}

// ---------- flash attention + gated adapter attention ----------
// v3: bh-per-XCD locality swizzle (1-D grid 1024, xcd=blk&7 owns bh xcd*16..+15),
// exp2-domain softmax, setprio on MFMA clusters. QBLK=128, 8 waves, dbuf K/V.
__global__ __launch_bounds__(512)
void k_attn(const u16* __restrict__ Q, const u16* __restrict__ Kg,
            const u16* __restrict__ Vt, const u16* __restrict__ AKg,
            const u16* __restrict__ AVg, const float* __restrict__ gate,
            u16* __restrict__ outp){
  __shared__ __align__(16) u16 Ks[2][64][128];
  __shared__ __align__(16) u16 Vs[2][128][64];
  __shared__ __align__(16) u16 Ps[8][16][64];

  // L2-locality swizzle: XCD (blk&7) exclusively owns 16 consecutive bh
  const int blk = blockIdx.x;
  const int jj = blk >> 3;
  const int bh = (blk & 7) * 16 + (jj & 15);
  const int bx = jj >> 4;            // 0..7
  const int b = bh >> 5, h = bh & 31;
  const int q0 = bx * 128;
  const int tid = threadIdx.x;
  const int w = tid >> 6, l = tid & 63;
  const int lrow = l & 15, lgrp = l >> 4;

  const u16* Qb = Q  + (size_t)bh * (Sz * HDz) + (size_t)q0 * HDz;
  const u16* Kb = Kg + (size_t)bh * (Sz * HDz);
  const u16* Vb = Vt + (size_t)bh * (HDz * Sz);
  u16* PsB = &Ps[0][0][0];

  short8 aq[4];
#pragma unroll
  for (int kk = 0; kk < 4; kk++)
    aq[kk] = *(const short8*)&Qb[(size_t)(w*16 + lrow) * HDz + kk*32 + lgrp*8];

  const fx4 fz = {0.f, 0.f, 0.f, 0.f};
  fx4 o[8];
#pragma unroll
  for (int i = 0; i < 8; i++) o[i] = fz;
  float mrow[4], lsum[4];
#pragma unroll
  for (int r = 0; r < 4; r++){ mrow[r] = -1e30f; lsum[r] = 0.f; }

  // log2-domain softmax: scale2 = 1/sqrt(128) * log2(e)
  const float scale2 = 0.088388347648318447f * 1.4426950408889634f;
  const int qwbase = q0 + w * 16;
  const int qrowbase = qwbase + lgrp * 4;
  const int ktiles = 2 * bx + 2;

  auto STAGE = [&](int buf, int kt){
    const int k0 = kt * 64;
#pragma unroll
    for (int r = 0; r < 2; r++){
      int c = r * 512 + tid;
      int row = c >> 4, cs = c & 15;
      int gcs = cs ^ (row & 7);
      gload16(Kb + (size_t)(k0 + row) * HDz + gcs * 8, ((u16*)&Ks[buf][0][0]) + c * 8);
    }
#pragma unroll
    for (int r = 0; r < 2; r++){
      int c = r * 512 + tid;
      int row = c >> 3, cs = c & 7;
      int gcs = cs ^ (row & 7);
      gload16(Vb + (size_t)row * Sz + k0 + gcs * 8, ((u16*)&Vs[buf][0][0]) + c * 8);
    }
  };

  STAGE(0, 0);
  asm volatile("s_waitcnt vmcnt(0)" ::: "memory");
  bar();

  for (int kt = 0; kt < ktiles; kt++){
    const int cur = kt & 1;
    if (kt + 1 < ktiles) STAGE(cur ^ 1, kt + 1);
    const int k0 = kt * 64;

    if (k0 <= qwbase + 15){
      fx4 sc[4];
#pragma unroll
      for (int j = 0; j < 4; j++) sc[j] = fz;
      __builtin_amdgcn_s_setprio(1);
#pragma unroll
      for (int kk = 0; kk < 4; kk++){
#pragma unroll
        for (int j = 0; j < 4; j++){
          short8 bk = *ldsRd(&Ks[cur][0][0], 256, j*16 + lrow, kk*32 + lgrp*8);
          sc[j] = __builtin_amdgcn_mfma_f32_16x16x32_bf16(aq[kk], bk, sc[j], 0, 0, 0);
        }
      }
      __builtin_amdgcn_s_setprio(0);
      const bool domask = (k0 + 63 > qwbase);
      float tm[4];
#pragma unroll
      for (int r = 0; r < 4; r++){
        float mx = -1e30f;
#pragma unroll
        for (int j = 0; j < 4; j++){
          float v = sc[j][r] * scale2;
          if (domask){
            int kcol = k0 + j*16 + lrow;
            if (kcol > qrowbase + r) v = -1e30f;
          }
          sc[j][r] = v;
          mx = fmaxf(mx, v);
        }
#pragma unroll
        for (int d = 1; d < 16; d <<= 1) mx = fmaxf(mx, __shfl_xor(mx, d));
        tm[r] = mx;
      }
      // defer-max (THR = 11.5 log2-units ~ e^8 bound on P)
      if (!__all(tm[0] <= mrow[0] + 11.5f && tm[1] <= mrow[1] + 11.5f &&
                 tm[2] <= mrow[2] + 11.5f && tm[3] <= mrow[3] + 11.5f)){
        float esc[4];
#pragma unroll
        for (int r = 0; r < 4; r++){
          float nm = fmaxf(mrow[r], tm[r]);
          esc[r] = exp2f(mrow[r] - nm);
          mrow[r] = nm;
          lsum[r] *= esc[r];
        }
#pragma unroll
        for (int j = 0; j < 8; j++)
#pragma unroll
          for (int r = 0; r < 4; r++) o[j][r] *= esc[r];
      }
#pragma unroll
      for (int r = 0; r < 4; r++){
        float s = 0.f;
#pragma unroll
        for (int j = 0; j < 4; j++){
          float p = exp2f(sc[j][r] - mrow[r]);
          sc[j][r] = p;
          s += p;
        }
#pragma unroll
        for (int d = 1; d < 16; d <<= 1) s += __shfl_xor(s, d);
        lsum[r] += s;
      }
#pragma unroll
      for (int j = 0; j < 4; j++)
#pragma unroll
        for (int r = 0; r < 4; r++)
          *psPtr(PsB, w, lgrp*4 + r, j*16 + lrow) = f2b(sc[j][r]);
      __builtin_amdgcn_s_setprio(1);
#pragma unroll
      for (int kk = 0; kk < 2; kk++){
        short8 ap = *(const short8*)psPtr(PsB, w, lrow, kk*32 + lgrp*8);
#pragma unroll
        for (int j = 0; j < 8; j++){
          short8 bv = *ldsRd(&Vs[cur][0][0], 128, j*16 + lrow, kk*32 + lgrp*8);
          o[j] = __builtin_amdgcn_mfma_f32_16x16x32_bf16(ap, bv, o[j], 0, 0, 0);
        }
      }
      __builtin_amdgcn_s_setprio(0);
    }

    asm volatile("s_waitcnt vmcnt(0)" ::: "memory");
    bar();
  }

#pragma unroll
  for (int j = 0; j < 8; j++)
#pragma unroll
    for (int r = 0; r < 4; r++) o[j][r] /= lsum[r];

  // adapter attention (K/V direct from global; once per block)
  fx4 s2 = fz;
  const u16* AKb = AKg + (size_t)bh * (16 * HDz);
#pragma unroll
  for (int kk = 0; kk < 4; kk++){
    short8 bk = *(const short8*)&AKb[(size_t)lrow * HDz + kk*32 + lgrp*8];
    s2 = __builtin_amdgcn_mfma_f32_16x16x32_bf16(aq[kk], bk, s2, 0, 0, 0);
  }
  const float g = tanhf(gate[h]);
#pragma unroll
  for (int r = 0; r < 4; r++){
    float v = s2[r] * scale2;
    if (lrow >= ALz) v = -1e30f;
    float mx = v;
#pragma unroll
    for (int d = 1; d < 16; d <<= 1) mx = fmaxf(mx, __shfl_xor(mx, d));
    float p = exp2f(v - mx);
    float s = p;
#pragma unroll
    for (int d = 1; d < 16; d <<= 1) s += __shfl_xor(s, d);
    float p2 = g * p / s;
    *psPtr(PsB, w, lgrp*4 + r, lrow) = f2b(p2);
    *psPtr(PsB, w, lgrp*4 + r, 16 + lrow) = 0;
  }
  {
    const u16* AVb = AVg + (size_t)bh * (HDz * 32);
    short8 ap = *(const short8*)psPtr(PsB, w, lrow, lgrp*8);
#pragma unroll
    for (int j = 0; j < 8; j++){
      short8 bv = *(const short8*)&AVb[(size_t)(j*16 + lrow) * 32 + lgrp*8];
      o[j] = __builtin_amdgcn_mfma_f32_16x16x32_bf16(ap, bv, o[j], 0, 0, 0);
    }
  }

  u16* ob = outp + (size_t)(b * Sz + q0) * DIMz + h * HDz;
#pragma unroll
  for (int j = 0; j < 8; j++)
#pragma unroll
    for (int r = 0; r < 4; r++){
      int row = w*16 + lgrp*4 + r;
      ob[(size_t)row * DIMz + j*16 + lrow] = f2b(o[j][r]);
    }
}

// ---------- host ----------
extern "C" void kernel_launch(void* const* d_in, const int* in_sizes, int n_in,
                              void* d_out, int out_size, void* d_ws, size_t ws_size,
                              hipStream_t stream){
  const float* x    = (const float*)d_in[0];
  const float* adap = (const float*)d_in[1];
  const float* wq   = (const float*)d_in[2];
  const float* wk   = (const float*)d_in[3];
  const float* wv   = (const float*)d_in[4];
  const float* wo   = (const float*)d_in[5];
  const float* lq1  = (const float*)d_in[6];
  const float* lq2  = (const float*)d_in[7];
  const float* lk1  = (const float*)d_in[8];
  const float* lk2  = (const float*)d_in[9];
  const float* lv1  = (const float*)d_in[10];
  const float* lv2  = (const float*)d_in[11];
  const float* lo1  = (const float*)d_in[12];
  const float* lo2  = (const float*)d_in[13];
  const float* gate = (const float*)d_in[14];
  const float* fcos = (const float*)d_in[15];
  const float* fsin = (const float*)d_in[16];

  const size_t MB = 1024 * 1024;
  char* ws = (char*)d_ws;
  u16*  Xcat = (u16*)(ws);
  u16*  Wb   = (u16*)(ws + 34 * MB);
  u16*  xq   = (u16*)(ws + 66 * MB);
  u16*  xk   = (u16*)(ws + 100 * MB);
  u16*  xv   = (u16*)(ws + 134 * MB);
  u16*  Vt   = (u16*)(ws + 168 * MB);
  float* t   = (float*)(ws + 168 * MB);
  u16*  l1b  = (u16*)(ws + 200 * MB);
  u16*  AKb  = (u16*)(ws + 201 * MB);
  u16*  AVb  = (u16*)(ws + 201 * MB + 512 * 1024);
  u16*  Qb = Xcat;
  u16*  Kb = Wb;
  u16*  attn = xq;
  float* out = (float*)d_out;

  dim3 blk(256);
  const int MCAT = 4352;
  const u16* Xad = Xcat + (size_t)4096 * 4096;

  k_xcat<<<dim3(MCAT * 4096 / 1024), blk, 0, stream>>>(x, adap, Xcat);

  k_f2b_pad<<<dim3(4096 * 4096 / 1024), blk, 0, stream>>>(wq, Wb, 4096, 4096, 4096);
  gemm_nt256<<<dim3(256), dim3(512), 0, stream>>>(Xcat, Wb, xq, 4096, 4096, 1, 16);
  k_f2b_pad<<<dim3(4096 * 4096 / 1024), blk, 0, stream>>>(wk, Wb, 4096, 4096, 4096);
  gemm_nt256<<<dim3(256), dim3(512), 0, stream>>>(Xcat, Wb, xk, 4096, 4096, 1, 16);
  k_adgemm<<<dim3(64), blk, 0, stream>>>(Xad, Wb, xk + (size_t)4096 * 4096, 4096, 4096);
  k_f2b_pad<<<dim3(4096 * 4096 / 1024), blk, 0, stream>>>(wv, Wb, 4096, 4096, 4096);
  gemm_nt256<<<dim3(256), dim3(512), 0, stream>>>(Xcat, Wb, xv, 4096, 4096, 1, 16);
  k_adgemm<<<dim3(64), blk, 0, stream>>>(Xad, Wb, xv + (size_t)4096 * 4096, 4096, 4096);

  k_l1cat<<<dim3(128 * 4096 / 1024), blk, 0, stream>>>(lq1, lk1, lv1, l1b);
  gemm_nt<<<dim3(1, 32), blk, 0, stream>>>(Xcat, l1b, t, 4096, 128, 4096, 0);
  k_lora_add_b<<<dim3(16, 4096), blk, 0, stream>>>(xq, t, lq2, 0);
  k_lora_add_b<<<dim3(16, 4096), blk, 0, stream>>>(xk, t, lk2, 16);
  k_lora_add_b<<<dim3(16, 4096), blk, 0, stream>>>(xv, t, lv2, 32);

  k_rope<<<dim3(4096), blk, 0, stream>>>(xq, Qb, fcos, fsin);
  k_rope<<<dim3(4096), blk, 0, stream>>>(xk, Kb, fcos, fsin);
  k_vtrans<<<dim3(16, 128), blk, 0, stream>>>(xv, Vt);
  k_adresh<<<dim3(128), blk, 0, stream>>>(xk + (size_t)4096 * 4096,
                                          xv + (size_t)4096 * 4096, AKb, AVb);

  k_attn<<<dim3(1024), dim3(512), 0, stream>>>(Qb, Kb, Vt, AKb, AVb, gate, attn);

  k_f2b_pad<<<dim3(4096 * 4096 / 1024), blk, 0, stream>>>(wo, Wb, 4096, 4096, 4096);
  gemm_nt256<<<dim3(256), dim3(512), 0, stream>>>(attn, Wb, out, 4096, 4096, 0, 16);
  k_f2b_pad<<<dim3(128 * 4096 / 1024), blk, 0, stream>>>(lo1, l1b, 16, 4096, 128);
  gemm_nt<<<dim3(1, 32), blk, 0, stream>>>(attn, l1b, t, 4096, 128, 4096, 0);
  k_lora_add_f<<<dim3(16, 4096), blk, 0, stream>>>(out, t, lo2, 0);
}